// Round 1
// baseline (1185.191 us; speedup 1.0000x reference)
//
#include <hip/hip_runtime.h>
#include <cstdint>
#include <math.h>

#define DEV __device__ __forceinline__

static constexpr int BQ = 8, SEQN = 1000, CIN = 32, NH = 8;
static constexpr int NLAY = 4;
static constexpr int NTOT_C = 1365;
static constexpr int M_REAL = BQ * NTOT_C;   // 10920
static constexpr int M_PAD  = 11008;         // 86 * 128

DEV float bf2f(unsigned short u){ return __uint_as_float(((unsigned)u) << 16); }
DEV unsigned short f2bf(float f){
  unsigned u = __float_as_uint(f);
  u += 0x7fffu + ((u >> 16) & 1u);
  return (unsigned short)(u >> 16);
}

typedef __bf16 bf16x8 __attribute__((ext_vector_type(8)));
typedef float  f32x4  __attribute__((ext_vector_type(4)));

#define GLD_LDS16(gp, lp) __builtin_amdgcn_global_load_lds( \
    (const __attribute__((address_space(1))) void*)(gp), \
    (__attribute__((address_space(3))) void*)(lp), 16, 0, 0)

// ---------------- conv1d (k=3 circular) + sinusoid PE, writes level-0 rows ----------------
__global__ __launch_bounds__(256) void conv_pe_kernel(const float* __restrict__ x,
    const float* __restrict__ w, float* __restrict__ seqf)
{
  int bs = blockIdx.x;
  int b = bs >> 10, s = bs & 1023;
  float* outp = seqf + ((size_t)b * NTOT_C + s) * 512;
  int t = threadIdx.x;
  if (s >= SEQN){ outp[t] = 0.f; outp[t + 256] = 0.f; return; }
  __shared__ float xs[3][32];
  if (t < 96){
    int kk = t >> 5, c = t & 31;
    int ss = s + kk - 1;
    ss = (ss < 0) ? SEQN - 1 : (ss >= SEQN ? 0 : ss);
    xs[kk][c] = x[((size_t)b * SEQN + ss) * CIN + c];
  }
  __syncthreads();
  #pragma unroll
  for (int half = 0; half < 2; half++){
    int dd = t + half * 256;
    const float* wd = w + (size_t)dd * 96;
    float acc = 0.f;
    #pragma unroll
    for (int c = 0; c < CIN; c++){
      acc += xs[0][c] * wd[c*3+0] + xs[1][c] * wd[c*3+1] + xs[2][c] * wd[c*3+2];
    }
    double e2 = (double)(dd & ~1);
    double dv = pow(10000.0, e2 / 512.0);
    double ang = (double)s / dv;
    double pv = (dd & 1) ? cos(ang) : sin(ang);
    outp[dd] = acc + (float)pv;
  }
}

// ---------------- max-pool one pyramid level ----------------
__global__ __launch_bounds__(256) void pool_kernel(float* __restrict__ seqf,
    int inOff, int outOff, int outSz)
{
  int e = blockIdx.x * 256 + threadIdx.x;
  int d = e & 511;
  int r = e >> 9;
  int i = r % outSz;
  int b = r / outSz;
  const float* src = seqf + ((size_t)b * NTOT_C + inOff + 4 * i) * 512 + d;
  float m = fmaxf(fmaxf(src[0], src[512]), fmaxf(src[1024], src[1536]));
  seqf[((size_t)b * NTOT_C + outOff + i) * 512 + d] = m;
}

// ---------------- LayerNorm (optional residual), emits fp32 + bf16 ----------------
template<bool RES>
__global__ __launch_bounds__(256) void ln_kernel(const float* __restrict__ xin,
    const float* __restrict__ rin, float* __restrict__ outf, unsigned short* __restrict__ outb,
    const float* __restrict__ sg, const float* __restrict__ bg, int M)
{
  int row = blockIdx.x;
  int t = threadIdx.x;
  size_t base = (size_t)row * 512;
  if (row >= M){ outb[base + t] = 0; outb[base + t + 256] = 0; return; }
  float v0 = xin[base + t], v1 = xin[base + t + 256];
  if (RES){ v0 += rin[base + t]; v1 += rin[base + t + 256]; }
  __shared__ float red1[4], red2[4];
  int wv = t >> 6;
  float sall = v0 + v1;
  #pragma unroll
  for (int o = 32; o; o >>= 1) sall += __shfl_xor(sall, o, 64);
  if ((t & 63) == 0) red1[wv] = sall;
  __syncthreads();
  float mean = (red1[0] + red1[1] + red1[2] + red1[3]) * (1.f / 512.f);
  float d0 = v0 - mean, d1 = v1 - mean;
  float sq = d0 * d0 + d1 * d1;
  #pragma unroll
  for (int o = 32; o; o >>= 1) sq += __shfl_xor(sq, o, 64);
  if ((t & 63) == 0) red2[wv] = sq;
  __syncthreads();
  float var = (red2[0] + red2[1] + red2[2] + red2[3]) * (1.f / 512.f);
  float rstd = 1.f / sqrtf(var + 1e-5f);
  float y0 = d0 * rstd * sg[t] + bg[t];
  float y1 = d1 * rstd * sg[t + 256] + bg[t + 256];
  outf[base + t] = y0; outf[base + t + 256] = y1;
  outb[base + t] = f2bf(y0); outb[base + t + 256] = f2bf(y1);
}

// ---------------- weight fp32 (K,N) -> bf16 transposed (N,K) ----------------
__global__ __launch_bounds__(256) void wconv_kernel(const float* __restrict__ w,
    unsigned short* __restrict__ wt, int K, int N, size_t sStride, size_t dStride)
{
  __shared__ float tile[32][33];
  const float* wl = w + blockIdx.z * sStride;
  unsigned short* wtl = wt + blockIdx.z * dStride;
  int n0 = blockIdx.x * 32, k0 = blockIdx.y * 32;
  int c = threadIdx.x & 31, r8 = threadIdx.x >> 5;
  #pragma unroll
  for (int p = 0; p < 4; p++){ int r = r8 + p * 8; tile[r][c] = wl[(size_t)(k0 + r) * N + n0 + c]; }
  __syncthreads();
  #pragma unroll
  for (int p = 0; p < 4; p++){ int r = r8 + p * 8; wtl[(size_t)(n0 + r) * K + k0 + c] = f2bf(tile[c][r]); }
}

// ---------------- bf16 MFMA GEMM: C(M,N) = A(M,K) * Wt(N,K)^T ----------------
// EPI: 0 = f32 store, 1 = bf16 store, 2 = bias+gelu -> bf16, 3 = bias -> f32
template<int EPI>
__global__ __launch_bounds__(256) void gemm_kernel(
    const unsigned short* __restrict__ A, const unsigned short* __restrict__ Wt,
    float* __restrict__ Cf, unsigned short* __restrict__ Cb,
    const float* __restrict__ bias, int N, int K)
{
  __shared__ __align__(16) unsigned short As[128 * 32];
  __shared__ __align__(16) unsigned short Bs[128 * 32];
  const int tid = threadIdx.x;
  const int wv = tid >> 6, lane = tid & 63;
  const int m0 = blockIdx.x * 128, n0 = blockIdx.y * 128;
  const int wm = (wv >> 1) * 64, wn = (wv & 1) * 64;
  const int r16 = lane & 15, g = lane >> 4;

  const unsigned short* gA = A + (size_t)(m0 + 32 * wv + (lane >> 2)) * K + (lane & 3) * 8;
  const unsigned short* gB = Wt + (size_t)(n0 + 32 * wv + (lane >> 2)) * K + (lane & 3) * 8;
  unsigned short* lA = As + wv * 1024;
  unsigned short* lB = Bs + wv * 1024;

  f32x4 acc[4][4] = {};

  for (int k0 = 0; k0 < K; k0 += 32){
    GLD_LDS16(gA + k0,          lA);
    GLD_LDS16(gA + k0 + 16 * K, lA + 512);
    GLD_LDS16(gB + k0,          lB);
    GLD_LDS16(gB + k0 + 16 * K, lB + 512);
    __syncthreads();
    bf16x8 av[4], bv[4];
    #pragma unroll
    for (int m = 0; m < 4; m++)
      av[m] = *reinterpret_cast<const bf16x8*>(&As[((wm + m * 16 + r16) * 4 + g) * 8]);
    #pragma unroll
    for (int n = 0; n < 4; n++)
      bv[n] = *reinterpret_cast<const bf16x8*>(&Bs[((wn + n * 16 + r16) * 4 + g) * 8]);
    #pragma unroll
    for (int m = 0; m < 4; m++)
      #pragma unroll
      for (int n = 0; n < 4; n++)
        acc[m][n] = __builtin_amdgcn_mfma_f32_16x16x32_bf16(av[m], bv[n], acc[m][n], 0, 0, 0);
    __syncthreads();
  }

  const int colBase = n0 + wn + r16;
  #pragma unroll
  for (int m = 0; m < 4; m++){
    int rowBase = m0 + wm + m * 16 + g * 4;
    #pragma unroll
    for (int n = 0; n < 4; n++){
      int col = colBase + n * 16;
      float bsv = (EPI >= 2) ? bias[col] : 0.f;
      #pragma unroll
      for (int j = 0; j < 4; j++){
        float vlu = acc[m][n][j];
        if (EPI >= 2) vlu += bsv;
        if (EPI == 2) vlu = 0.5f * vlu * (1.f + erff(vlu * 0.70710678118654752f));
        size_t off = (size_t)(rowBase + j) * N + col;
        if (EPI == 1 || EPI == 2) Cb[off] = f2bf(vlu);
        else                      Cf[off] = vlu;
      }
    }
  }
}

// ---------------- sparse tree attention: one wave per (b,n,h) ----------------
__global__ __launch_bounds__(256) void attn_kernel(
    const unsigned short* __restrict__ qkv, unsigned short* __restrict__ ctx)
{
  int wid = blockIdx.x * 4 + (threadIdx.x >> 6);
  int lane = threadIdx.x & 63;
  int h = wid & 7;
  int tmp = wid >> 3;
  int n = tmp % NTOT_C;
  int b = tmp / NTOT_C;

  int i, sz, of, cb, par;
  if (n < 1024){ i = n;        sz = 1024; of = 0;    cb = -1;            par = 1024 + (i >> 2); }
  else if (n < 1280){ i = n - 1024; sz = 256; of = 1024; cb = 0    + 4 * i; par = 1280 + (i >> 2); }
  else if (n < 1344){ i = n - 1280; sz = 64;  of = 1280; cb = 1024 + 4 * i; par = 1344 + (i >> 2); }
  else if (n < 1360){ i = n - 1344; sz = 16;  of = 1344; cb = 1280 + 4 * i; par = 1360 + (i >> 2); }
  else if (n < 1364){ i = n - 1360; sz = 4;   of = 1360; cb = 1344 + 4 * i; par = 1364; }
  else { i = 0; sz = 1; of = 1364; cb = 1360; par = -1; }

  int nb[10];
  #pragma unroll
  for (int s5 = 0; s5 < 5; s5++){ int pos = i - 2 + s5; nb[s5] = (pos >= 0 && pos < sz) ? of + pos : -1; }
  #pragma unroll
  for (int r = 0; r < 4; r++) nb[5 + r] = (cb >= 0) ? cb + r : -1;
  nb[9] = par;

  size_t rowBase = ((size_t)b * NTOT_C) * 1536;
  float qd = bf2f(qkv[rowBase + (size_t)n * 1536 + h * 64 + lane]);

  float sc[10];
  #pragma unroll
  for (int j = 0; j < 10; j++){
    int id = nb[j] >= 0 ? nb[j] : n;
    float kd = bf2f(qkv[rowBase + (size_t)id * 1536 + 512 + h * 64 + lane]);
    float p = qd * kd;
    #pragma unroll
    for (int o = 32; o; o >>= 1) p += __shfl_xor(p, o, 64);
    sc[j] = (nb[j] >= 0) ? p * 0.125f : -1e30f;
  }
  float mx = sc[0];
  #pragma unroll
  for (int j = 1; j < 10; j++) mx = fmaxf(mx, sc[j]);
  float den = 0.f, accv = 0.f;
  #pragma unroll
  for (int j = 0; j < 10; j++){
    float wj = (nb[j] >= 0) ? expf(sc[j] - mx) : 0.f;
    den += wj;
    int id = nb[j] >= 0 ? nb[j] : n;
    float vd = bf2f(qkv[rowBase + (size_t)id * 1536 + 1024 + h * 64 + lane]);
    accv += wj * vd;
  }
  ctx[((size_t)b * NTOT_C + n) * 512 + h * 64 + lane] = f2bf(accv / den);
}

// ---------------- gather effective prefixes -> output ----------------
__global__ __launch_bounds__(256) void gather_kernel(const float* __restrict__ seqf,
    float* __restrict__ out)
{
  int e = blockIdx.x * 256 + threadIdx.x;
  int d = e & 511;
  int r = e >> 9;
  int j = r % 1334;
  int b = r / 1334;
  int src;
  if      (j < 1000) src = j;
  else if (j < 1250) src = j + 24;
  else if (j < 1313) src = j + 30;
  else if (j < 1333) src = j + 31;
  else               src = 1364;
  out[e] = seqf[((size_t)b * NTOT_C + src) * 512 + d];
}

extern "C" void kernel_launch(void* const* d_in, const int* in_sizes, int n_in,
                              void* d_out, int out_size, void* d_ws, size_t ws_size,
                              hipStream_t stream)
{
  const float* x      = (const float*)d_in[0];
  const float* conv_w = (const float*)d_in[1];
  const float* norm_s = (const float*)d_in[2];
  const float* norm_b = (const float*)d_in[3];
  const float* wq     = (const float*)d_in[4];
  const float* wk     = (const float*)d_in[5];
  const float* wv     = (const float*)d_in[6];
  const float* wo     = (const float*)d_in[7];
  const float* ln1_s  = (const float*)d_in[8];
  const float* ln1_b  = (const float*)d_in[9];
  const float* w1     = (const float*)d_in[10];
  const float* b1     = (const float*)d_in[11];
  const float* w2     = (const float*)d_in[12];
  const float* b2     = (const float*)d_in[13];
  const float* ln2_s  = (const float*)d_in[14];
  const float* ln2_b  = (const float*)d_in[15];
  float* out = (float*)d_out;

  char* ws = (char*)d_ws;
  size_t off = 0;
  auto alloc = [&](size_t bytes) -> char* {
    char* p = ws + off; off += (bytes + 255) & ~(size_t)255; return p;
  };
  unsigned short* qkvT = (unsigned short*)alloc((size_t)NLAY * 1536 * 512 * 2);
  unsigned short* woT  = (unsigned short*)alloc((size_t)NLAY * 512 * 512 * 2);
  unsigned short* w1T  = (unsigned short*)alloc((size_t)NLAY * 2048 * 512 * 2);
  unsigned short* w2T  = (unsigned short*)alloc((size_t)NLAY * 512 * 2048 * 2);
  float*          seqf = (float*)alloc((size_t)M_PAD * 512 * 4);
  unsigned short* seqb = (unsigned short*)alloc((size_t)M_PAD * 512 * 2);
  float*          buff = (float*)alloc((size_t)M_PAD * 512 * 4);
  unsigned short* qkvb = (unsigned short*)alloc((size_t)M_PAD * 1536 * 2);
  unsigned short* ctxb = (unsigned short*)alloc((size_t)M_PAD * 512 * 2);
  unsigned short* ffn1 = qkvb;  // alias: ffn1 (M_PAD x 2048) == qkvb + ctxb region

  // weight transforms (per launch; cheap)
  wconv_kernel<<<dim3(16,16,NLAY),256,0,stream>>>(wq, qkvT,              512,  512,  (size_t)512*512,  (size_t)1536*512);
  wconv_kernel<<<dim3(16,16,NLAY),256,0,stream>>>(wk, qkvT + 512*512,    512,  512,  (size_t)512*512,  (size_t)1536*512);
  wconv_kernel<<<dim3(16,16,NLAY),256,0,stream>>>(wv, qkvT + 1024*512,   512,  512,  (size_t)512*512,  (size_t)1536*512);
  wconv_kernel<<<dim3(16,16,NLAY),256,0,stream>>>(wo, woT,               512,  512,  (size_t)512*512,  (size_t)512*512);
  wconv_kernel<<<dim3(64,16,NLAY),256,0,stream>>>(w1, w1T,               512,  2048, (size_t)512*2048, (size_t)512*2048);
  wconv_kernel<<<dim3(16,64,NLAY),256,0,stream>>>(w2, w2T,               2048, 512,  (size_t)2048*512, (size_t)2048*512);

  // embedding + pyramid
  conv_pe_kernel<<<BQ * 1024, 256, 0, stream>>>(x, conv_w, seqf);
  const int psz[6]  = {1024, 256, 64, 16, 4, 1};
  const int poff[6] = {0, 1024, 1280, 1344, 1360, 1364};
  for (int l = 0; l < 5; l++)
    pool_kernel<<<(BQ * psz[l+1] * 512) / 256, 256, 0, stream>>>(seqf, poff[l], poff[l+1], psz[l+1]);
  ln_kernel<false><<<M_PAD, 256, 0, stream>>>(seqf, nullptr, seqf, seqb, norm_s, norm_b, M_REAL);

  for (int l = 0; l < NLAY; l++){
    gemm_kernel<1><<<dim3(86,12),256,0,stream>>>(seqb, qkvT + (size_t)l*1536*512, nullptr, qkvb, nullptr, 1536, 512);
    attn_kernel<<<(BQ * NTOT_C * NH) / 4, 256, 0, stream>>>(qkvb, ctxb);
    gemm_kernel<0><<<dim3(86,4),256,0,stream>>>(ctxb, woT + (size_t)l*512*512, buff, nullptr, nullptr, 512, 512);
    ln_kernel<true><<<M_PAD,256,0,stream>>>(seqf, buff, seqf, seqb, ln1_s + l*512, ln1_b + l*512, M_REAL);
    gemm_kernel<2><<<dim3(86,16),256,0,stream>>>(seqb, w1T + (size_t)l*2048*512, nullptr, ffn1, b1 + l*2048, 2048, 512);
    gemm_kernel<3><<<dim3(86,4),256,0,stream>>>(ffn1, w2T + (size_t)l*512*2048, buff, nullptr, b2 + l*512, 512, 2048);
    ln_kernel<true><<<M_PAD,256,0,stream>>>(seqf, buff, seqf, seqb, ln2_s + l*512, ln2_b + l*512, M_REAL);
  }

  gather_kernel<<<(BQ * 1334 * 512) / 256, 256, 0, stream>>>(seqf, out);
}

// Round 2
// 1185.177 us; speedup vs baseline: 1.0000x; 1.0000x over previous
//
#include <hip/hip_runtime.h>
#include <cstdint>
#include <math.h>

#define DEV __device__ __forceinline__

static constexpr int BQ = 8, SEQN = 1000, CIN = 32, NH = 8;
static constexpr int NLAY = 4;
static constexpr int NTOT_C = 1365;
static constexpr int M_REAL = BQ * NTOT_C;   // 10920
static constexpr int M_PAD  = 11008;         // 86 * 128

DEV float bf2f(unsigned short u){ return __uint_as_float(((unsigned)u) << 16); }
DEV unsigned short f2bf(float f){
  unsigned u = __float_as_uint(f);
  u += 0x7fffu + ((u >> 16) & 1u);
  return (unsigned short)(u >> 16);
}

typedef __bf16 bf16x8 __attribute__((ext_vector_type(8)));
typedef float  f32x4  __attribute__((ext_vector_type(4)));

#define GLD_LDS16(gp, lp) __builtin_amdgcn_global_load_lds( \
    (const __attribute__((address_space(1))) void*)(gp), \
    (__attribute__((address_space(3))) void*)(lp), 16, 0, 0)

// ---------------- conv1d (k=3 circular) + sinusoid PE, writes level-0 rows ----------------
__global__ __launch_bounds__(256) void conv_pe_kernel(const float* __restrict__ x,
    const float* __restrict__ w, float* __restrict__ seqf)
{
  int bs = blockIdx.x;
  int b = bs >> 10, s = bs & 1023;
  float* outp = seqf + ((size_t)b * NTOT_C + s) * 512;
  int t = threadIdx.x;
  if (s >= SEQN){ outp[t] = 0.f; outp[t + 256] = 0.f; return; }
  __shared__ float xs[3][32];
  if (t < 96){
    int kk = t >> 5, c = t & 31;
    int ss = s + kk - 1;
    ss = (ss < 0) ? SEQN - 1 : (ss >= SEQN ? 0 : ss);
    xs[kk][c] = x[((size_t)b * SEQN + ss) * CIN + c];
  }
  __syncthreads();
  #pragma unroll
  for (int half = 0; half < 2; half++){
    int dd = t + half * 256;
    const float* wd = w + (size_t)dd * 96;
    float acc = 0.f;
    #pragma unroll
    for (int c = 0; c < CIN; c++){
      acc += xs[0][c] * wd[c*3+0] + xs[1][c] * wd[c*3+1] + xs[2][c] * wd[c*3+2];
    }
    double e2 = (double)(dd & ~1);
    double dv = pow(10000.0, e2 / 512.0);
    double ang = (double)s / dv;
    double pv = (dd & 1) ? cos(ang) : sin(ang);
    outp[dd] = acc + (float)pv;
  }
}

// ---------------- max-pool one pyramid level ----------------
__global__ __launch_bounds__(256) void pool_kernel(float* __restrict__ seqf,
    int inOff, int outOff, int outSz)
{
  int e = blockIdx.x * 256 + threadIdx.x;
  int d = e & 511;
  int r = e >> 9;
  int i = r % outSz;
  int b = r / outSz;
  const float* src = seqf + ((size_t)b * NTOT_C + inOff + 4 * i) * 512 + d;
  float m = fmaxf(fmaxf(src[0], src[512]), fmaxf(src[1024], src[1536]));
  seqf[((size_t)b * NTOT_C + outOff + i) * 512 + d] = m;
}

// ---------------- LayerNorm (optional residual), emits fp32 + bf16 ----------------
template<bool RES>
__global__ __launch_bounds__(256) void ln_kernel(const float* __restrict__ xin,
    const float* __restrict__ rin, float* __restrict__ outf, unsigned short* __restrict__ outb,
    const float* __restrict__ sg, const float* __restrict__ bg, int M)
{
  int row = blockIdx.x;
  int t = threadIdx.x;
  size_t base = (size_t)row * 512;
  if (row >= M){ outb[base + t] = 0; outb[base + t + 256] = 0; return; }
  float v0 = xin[base + t], v1 = xin[base + t + 256];
  if (RES){ v0 += rin[base + t]; v1 += rin[base + t + 256]; }
  __shared__ float red1[4], red2[4];
  int wv = t >> 6;
  float sall = v0 + v1;
  #pragma unroll
  for (int o = 32; o; o >>= 1) sall += __shfl_xor(sall, o, 64);
  if ((t & 63) == 0) red1[wv] = sall;
  __syncthreads();
  float mean = (red1[0] + red1[1] + red1[2] + red1[3]) * (1.f / 512.f);
  float d0 = v0 - mean, d1 = v1 - mean;
  float sq = d0 * d0 + d1 * d1;
  #pragma unroll
  for (int o = 32; o; o >>= 1) sq += __shfl_xor(sq, o, 64);
  if ((t & 63) == 0) red2[wv] = sq;
  __syncthreads();
  float var = (red2[0] + red2[1] + red2[2] + red2[3]) * (1.f / 512.f);
  float rstd = 1.f / sqrtf(var + 1e-5f);
  float y0 = d0 * rstd * sg[t] + bg[t];
  float y1 = d1 * rstd * sg[t + 256] + bg[t + 256];
  outf[base + t] = y0; outf[base + t + 256] = y1;
  outb[base + t] = f2bf(y0); outb[base + t + 256] = f2bf(y1);
}

// ---------------- weight fp32 (K,N) -> bf16 transposed (N,K) ----------------
__global__ __launch_bounds__(256) void wconv_kernel(const float* __restrict__ w,
    unsigned short* __restrict__ wt, int K, int N, size_t sStride, size_t dStride)
{
  __shared__ float tile[32][33];
  const float* wl = w + blockIdx.z * sStride;
  unsigned short* wtl = wt + blockIdx.z * dStride;
  int n0 = blockIdx.x * 32, k0 = blockIdx.y * 32;
  int c = threadIdx.x & 31, r8 = threadIdx.x >> 5;
  #pragma unroll
  for (int p = 0; p < 4; p++){ int r = r8 + p * 8; tile[r][c] = wl[(size_t)(k0 + r) * N + n0 + c]; }
  __syncthreads();
  #pragma unroll
  for (int p = 0; p < 4; p++){ int r = r8 + p * 8; wtl[(size_t)(n0 + r) * K + k0 + c] = f2bf(tile[c][r]); }
}

// ---------------- bf16 MFMA GEMM: C(M,N) = A(M,K) * Wt(N,K)^T ----------------
// EPI: 0 = f32 store, 1 = bf16 store, 2 = bias+gelu -> bf16, 3 = bias -> f32
template<int EPI>
__global__ __launch_bounds__(256) void gemm_kernel(
    const unsigned short* __restrict__ A, const unsigned short* __restrict__ Wt,
    float* __restrict__ Cf, unsigned short* __restrict__ Cb,
    const float* __restrict__ bias, int N, int K)
{
  __shared__ __align__(16) unsigned short As[128 * 32];
  __shared__ __align__(16) unsigned short Bs[128 * 32];
  const int tid = threadIdx.x;
  const int wv = tid >> 6, lane = tid & 63;
  const int m0 = blockIdx.x * 128, n0 = blockIdx.y * 128;
  const int wm = (wv >> 1) * 64, wn = (wv & 1) * 64;
  const int r16 = lane & 15, g = lane >> 4;

  const unsigned short* gA = A + (size_t)(m0 + 32 * wv + (lane >> 2)) * K + (lane & 3) * 8;
  const unsigned short* gB = Wt + (size_t)(n0 + 32 * wv + (lane >> 2)) * K + (lane & 3) * 8;
  unsigned short* lA = As + wv * 1024;
  unsigned short* lB = Bs + wv * 1024;

  f32x4 acc[4][4] = {};

  for (int k0 = 0; k0 < K; k0 += 32){
    GLD_LDS16(gA + k0,          lA);
    GLD_LDS16(gA + k0 + 16 * K, lA + 512);
    GLD_LDS16(gB + k0,          lB);
    GLD_LDS16(gB + k0 + 16 * K, lB + 512);
    __syncthreads();
    bf16x8 av[4], bv[4];
    #pragma unroll
    for (int m = 0; m < 4; m++)
      av[m] = *reinterpret_cast<const bf16x8*>(&As[((wm + m * 16 + r16) * 4 + g) * 8]);
    #pragma unroll
    for (int n = 0; n < 4; n++)
      bv[n] = *reinterpret_cast<const bf16x8*>(&Bs[((wn + n * 16 + r16) * 4 + g) * 8]);
    #pragma unroll
    for (int m = 0; m < 4; m++)
      #pragma unroll
      for (int n = 0; n < 4; n++)
        acc[m][n] = __builtin_amdgcn_mfma_f32_16x16x32_bf16(av[m], bv[n], acc[m][n], 0, 0, 0);
    __syncthreads();
  }

  const int colBase = n0 + wn + r16;
  #pragma unroll
  for (int m = 0; m < 4; m++){
    int rowBase = m0 + wm + m * 16 + g * 4;
    #pragma unroll
    for (int n = 0; n < 4; n++){
      int col = colBase + n * 16;
      float bsv = (EPI >= 2) ? bias[col] : 0.f;
      #pragma unroll
      for (int j = 0; j < 4; j++){
        float vlu = acc[m][n][j];
        if (EPI >= 2) vlu += bsv;
        if (EPI == 2) vlu = 0.5f * vlu * (1.f + erff(vlu * 0.70710678118654752f));
        size_t off = (size_t)(rowBase + j) * N + col;
        if (EPI == 1 || EPI == 2) Cb[off] = f2bf(vlu);
        else                      Cf[off] = vlu;
      }
    }
  }
}

// ---------------- sparse tree attention: one wave per (b,n,h) ----------------
__global__ __launch_bounds__(256) void attn_kernel(
    const unsigned short* __restrict__ qkv, unsigned short* __restrict__ ctx)
{
  int wid = blockIdx.x * 4 + (threadIdx.x >> 6);
  int lane = threadIdx.x & 63;
  int h = wid & 7;
  int tmp = wid >> 3;
  int n = tmp % NTOT_C;
  int b = tmp / NTOT_C;

  int i, sz, of, cb, par;
  if (n < 1024){ i = n;        sz = 1024; of = 0;    cb = -1;            par = 1024 + (i >> 2); }
  else if (n < 1280){ i = n - 1024; sz = 256; of = 1024; cb = 0    + 4 * i; par = 1280 + (i >> 2); }
  else if (n < 1344){ i = n - 1280; sz = 64;  of = 1280; cb = 1024 + 4 * i; par = 1344 + (i >> 2); }
  else if (n < 1360){ i = n - 1344; sz = 16;  of = 1344; cb = 1280 + 4 * i; par = 1360 + (i >> 2); }
  else if (n < 1364){ i = n - 1360; sz = 4;   of = 1360; cb = 1344 + 4 * i; par = 1364; }
  else { i = 0; sz = 1; of = 1364; cb = 1360; par = -1; }

  int nb[10];
  #pragma unroll
  for (int s5 = 0; s5 < 5; s5++){ int pos = i - 2 + s5; nb[s5] = (pos >= 0 && pos < sz) ? of + pos : -1; }
  #pragma unroll
  for (int r = 0; r < 4; r++) nb[5 + r] = (cb >= 0) ? cb + r : -1;
  nb[9] = par;

  size_t rowBase = ((size_t)b * NTOT_C) * 1536;
  float qd = bf2f(qkv[rowBase + (size_t)n * 1536 + h * 64 + lane]);

  float sc[10];
  #pragma unroll
  for (int j = 0; j < 10; j++){
    int id = nb[j] >= 0 ? nb[j] : n;
    float kd = bf2f(qkv[rowBase + (size_t)id * 1536 + 512 + h * 64 + lane]);
    float p = qd * kd;
    #pragma unroll
    for (int o = 32; o; o >>= 1) p += __shfl_xor(p, o, 64);
    sc[j] = (nb[j] >= 0) ? p * 0.125f : -1e30f;
  }
  float mx = sc[0];
  #pragma unroll
  for (int j = 1; j < 10; j++) mx = fmaxf(mx, sc[j]);
  float den = 0.f, accv = 0.f;
  #pragma unroll
  for (int j = 0; j < 10; j++){
    float wj = (nb[j] >= 0) ? expf(sc[j] - mx) : 0.f;
    den += wj;
    int id = nb[j] >= 0 ? nb[j] : n;
    float vd = bf2f(qkv[rowBase + (size_t)id * 1536 + 1024 + h * 64 + lane]);
    accv += wj * vd;
  }
  ctx[((size_t)b * NTOT_C + n) * 512 + h * 64 + lane] = f2bf(accv / den);
}

// ---------------- gather effective prefixes -> output ----------------
__global__ __launch_bounds__(256) void gather_kernel(const float* __restrict__ seqf,
    float* __restrict__ out)
{
  int e = blockIdx.x * 256 + threadIdx.x;
  int d = e & 511;
  int r = e >> 9;
  int j = r % 1334;
  int b = r / 1334;
  int src;
  if      (j < 1000) src = j;
  else if (j < 1250) src = j + 24;
  else if (j < 1313) src = j + 30;
  else if (j < 1333) src = j + 31;
  else               src = 1364;
  out[e] = seqf[((size_t)b * NTOT_C + src) * 512 + d];
}

extern "C" void kernel_launch(void* const* d_in, const int* in_sizes, int n_in,
                              void* d_out, int out_size, void* d_ws, size_t ws_size,
                              hipStream_t stream)
{
  const float* x      = (const float*)d_in[0];
  const float* conv_w = (const float*)d_in[1];
  const float* norm_s = (const float*)d_in[2];
  const float* norm_b = (const float*)d_in[3];
  const float* wq     = (const float*)d_in[4];
  const float* wk     = (const float*)d_in[5];
  const float* wv     = (const float*)d_in[6];
  const float* wo     = (const float*)d_in[7];
  const float* ln1_s  = (const float*)d_in[8];
  const float* ln1_b  = (const float*)d_in[9];
  const float* w1     = (const float*)d_in[10];
  const float* b1     = (const float*)d_in[11];
  const float* w2     = (const float*)d_in[12];
  const float* b2     = (const float*)d_in[13];
  const float* ln2_s  = (const float*)d_in[14];
  const float* ln2_b  = (const float*)d_in[15];
  float* out = (float*)d_out;

  char* ws = (char*)d_ws;
  size_t off = 0;
  auto alloc = [&](size_t bytes) -> char* {
    char* p = ws + off; off += (bytes + 255) & ~(size_t)255; return p;
  };
  unsigned short* qkvT = (unsigned short*)alloc((size_t)NLAY * 1536 * 512 * 2);
  unsigned short* woT  = (unsigned short*)alloc((size_t)NLAY * 512 * 512 * 2);
  unsigned short* w1T  = (unsigned short*)alloc((size_t)NLAY * 2048 * 512 * 2);
  unsigned short* w2T  = (unsigned short*)alloc((size_t)NLAY * 512 * 2048 * 2);
  float*          seqf = (float*)alloc((size_t)M_PAD * 512 * 4);
  unsigned short* seqb = (unsigned short*)alloc((size_t)M_PAD * 512 * 2);
  float*          buff = (float*)alloc((size_t)M_PAD * 512 * 4);
  unsigned short* qkvb = (unsigned short*)alloc((size_t)M_PAD * 1536 * 2);
  unsigned short* ctxb = (unsigned short*)alloc((size_t)M_PAD * 512 * 2);
  unsigned short* ffn1 = qkvb;  // alias: ffn1 (M_PAD x 2048) == qkvb + ctxb region

  // weight transforms (per launch; cheap)
  wconv_kernel<<<dim3(16,16,NLAY),256,0,stream>>>(wq, qkvT,              512,  512,  (size_t)512*512,  (size_t)1536*512);
  wconv_kernel<<<dim3(16,16,NLAY),256,0,stream>>>(wk, qkvT + 512*512,    512,  512,  (size_t)512*512,  (size_t)1536*512);
  wconv_kernel<<<dim3(16,16,NLAY),256,0,stream>>>(wv, qkvT + 1024*512,   512,  512,  (size_t)512*512,  (size_t)1536*512);
  wconv_kernel<<<dim3(16,16,NLAY),256,0,stream>>>(wo, woT,               512,  512,  (size_t)512*512,  (size_t)512*512);
  wconv_kernel<<<dim3(64,16,NLAY),256,0,stream>>>(w1, w1T,               512,  2048, (size_t)512*2048, (size_t)512*2048);
  wconv_kernel<<<dim3(16,64,NLAY),256,0,stream>>>(w2, w2T,               2048, 512,  (size_t)2048*512, (size_t)2048*512);

  // embedding + pyramid
  conv_pe_kernel<<<BQ * 1024, 256, 0, stream>>>(x, conv_w, seqf);
  const int psz[6]  = {1024, 256, 64, 16, 4, 1};
  const int poff[6] = {0, 1024, 1280, 1344, 1360, 1364};
  for (int l = 0; l < 5; l++)
    pool_kernel<<<(BQ * psz[l+1] * 512) / 256, 256, 0, stream>>>(seqf, poff[l], poff[l+1], psz[l+1]);
  ln_kernel<false><<<M_PAD, 256, 0, stream>>>(seqf, nullptr, seqf, seqb, norm_s, norm_b, M_REAL);

  for (int l = 0; l < NLAY; l++){
    gemm_kernel<1><<<dim3(86,12),256,0,stream>>>(seqb, qkvT + (size_t)l*1536*512, nullptr, qkvb, nullptr, 1536, 512);
    attn_kernel<<<(BQ * NTOT_C * NH) / 4, 256, 0, stream>>>(qkvb, ctxb);
    gemm_kernel<0><<<dim3(86,4),256,0,stream>>>(ctxb, woT + (size_t)l*512*512, buff, nullptr, nullptr, 512, 512);
    ln_kernel<true><<<M_PAD,256,0,stream>>>(seqf, buff, seqf, seqb, ln1_s + l*512, ln1_b + l*512, M_REAL);
    gemm_kernel<2><<<dim3(86,16),256,0,stream>>>(seqb, w1T + (size_t)l*2048*512, nullptr, ffn1, b1 + l*2048, 2048, 512);
    gemm_kernel<3><<<dim3(86,4),256,0,stream>>>(ffn1, w2T + (size_t)l*512*2048, buff, nullptr, b2 + l*512, 512, 2048);
    ln_kernel<true><<<M_PAD,256,0,stream>>>(seqf, buff, seqf, seqb, ln2_s + l*512, ln2_b + l*512, M_REAL);
  }

  gather_kernel<<<(BQ * 1334 * 512) / 256, 256, 0, stream>>>(seqf, out);
}

// Round 3
// 1033.907 us; speedup vs baseline: 1.1463x; 1.1463x over previous
//
#include <hip/hip_runtime.h>
#include <cstdint>
#include <math.h>

#define DEV __device__ __forceinline__

static constexpr int BQ = 8, SEQN = 1000, CIN = 32, NH = 8;
static constexpr int NLAY = 4;
static constexpr int NTOT_C = 1365;
static constexpr int M_REAL = BQ * NTOT_C;   // 10920
static constexpr int M_PAD  = 11008;         // 86 * 128

DEV float bf2f(unsigned short u){ return __uint_as_float(((unsigned)u) << 16); }
DEV unsigned short f2bf(float f){
  unsigned u = __float_as_uint(f);
  u += 0x7fffu + ((u >> 16) & 1u);
  return (unsigned short)(u >> 16);
}

typedef __bf16 bf16x8 __attribute__((ext_vector_type(8)));
typedef float  f32x4  __attribute__((ext_vector_type(4)));

#define GLD_LDS16(gp, lp) __builtin_amdgcn_global_load_lds( \
    (const __attribute__((address_space(1))) void*)(gp), \
    (__attribute__((address_space(3))) void*)(lp), 16, 0, 0)

// ---------------- sinusoid PE table (fp32), SEQN x 512 ----------------
__global__ __launch_bounds__(256) void pe_kernel(float* __restrict__ pe)
{
  int idx = blockIdx.x * 256 + threadIdx.x;   // [0, SEQN*512)
  int d = idx & 511, s = idx >> 9;
  if (s >= SEQN) return;
  float e2 = (float)(d & ~1);
  // freq = 10000^(-e2/512) = exp2(-e2 * log2(10000)/512)
  float freq = exp2f(e2 * (-13.287712379549449f / 512.0f));
  float ang = (float)s * freq;
  pe[idx] = (d & 1) ? cosf(ang) : sinf(ang);
}

// ---------------- conv1d (k=3 circular), tiled: 64 s x 128 d per block ----------------
__global__ __launch_bounds__(256) void conv_kernel(const float* __restrict__ x,
    const float* __restrict__ w, const float* __restrict__ pe, float* __restrict__ seqf)
{
  __shared__ float ws_w[128 * 97];
  __shared__ __align__(16) float xs[66][32];
  int b = blockIdx.z, s0 = blockIdx.y * 64, d0 = blockIdx.x * 128;
  int tid = threadIdx.x;
  // stage weights (128 d-rows x 96) coalesced, pad stride 97 to kill bank conflicts
  for (int i = tid; i < 128 * 96; i += 256){
    int r = i / 96, c = i - r * 96;
    ws_w[r * 97 + c] = w[(size_t)(d0 + r) * 96 + c];
  }
  // stage x slice: rows cover global ss = s0-1 .. s0+64 (circular)
  for (int i = tid; i < 66 * 32; i += 256){
    int r = i >> 5, c = i & 31;
    int ss = s0 + r - 1;
    ss = (ss < 0) ? (ss + SEQN) : (ss >= SEQN ? ss - SEQN : ss);
    xs[r][c] = x[((size_t)b * SEQN + ss) * CIN + c];
  }
  __syncthreads();
  int dl = tid & 127, sh = tid >> 7;     // 128 d-lanes, 2 s-halves
  float wr[96];
  #pragma unroll
  for (int i = 0; i < 96; i++) wr[i] = ws_w[dl * 97 + i];
  int d = d0 + dl;
  for (int si = 0; si < 32; si++){
    int sl = sh * 32 + si;
    int s = s0 + sl;
    float acc = 0.f;
    #pragma unroll
    for (int kk = 0; kk < 3; kk++){
      const float* xr = xs[sl + kk];
      #pragma unroll
      for (int c = 0; c < 32; c++) acc += xr[c] * wr[c * 3 + kk];
    }
    float outv = (s < SEQN) ? acc + pe[(size_t)s * 512 + d] : 0.f;
    seqf[((size_t)b * NTOT_C + s) * 512 + d] = outv;
  }
}

// ---------------- max-pool one pyramid level ----------------
__global__ __launch_bounds__(256) void pool_kernel(float* __restrict__ seqf,
    int inOff, int outOff, int outSz)
{
  int e = blockIdx.x * 256 + threadIdx.x;
  int d = e & 511;
  int r = e >> 9;
  int i = r % outSz;
  int b = r / outSz;
  const float* src = seqf + ((size_t)b * NTOT_C + inOff + 4 * i) * 512 + d;
  float m = fmaxf(fmaxf(src[0], src[512]), fmaxf(src[1024], src[1536]));
  seqf[((size_t)b * NTOT_C + outOff + i) * 512 + d] = m;
}

// ---------------- LayerNorm (optional residual), emits fp32 + bf16 ----------------
template<bool RES>
__global__ __launch_bounds__(256) void ln_kernel(const float* __restrict__ xin,
    const float* __restrict__ rin, float* __restrict__ outf, unsigned short* __restrict__ outb,
    const float* __restrict__ sg, const float* __restrict__ bg, int M)
{
  int row = blockIdx.x;
  int t = threadIdx.x;
  size_t base = (size_t)row * 512;
  if (row >= M){ outb[base + t] = 0; outb[base + t + 256] = 0; return; }
  float v0 = xin[base + t], v1 = xin[base + t + 256];
  if (RES){ v0 += rin[base + t]; v1 += rin[base + t + 256]; }
  __shared__ float red1[4], red2[4];
  int wv = t >> 6;
  float sall = v0 + v1;
  #pragma unroll
  for (int o = 32; o; o >>= 1) sall += __shfl_xor(sall, o, 64);
  if ((t & 63) == 0) red1[wv] = sall;
  __syncthreads();
  float mean = (red1[0] + red1[1] + red1[2] + red1[3]) * (1.f / 512.f);
  float d0 = v0 - mean, d1 = v1 - mean;
  float sq = d0 * d0 + d1 * d1;
  #pragma unroll
  for (int o = 32; o; o >>= 1) sq += __shfl_xor(sq, o, 64);
  if ((t & 63) == 0) red2[wv] = sq;
  __syncthreads();
  float var = (red2[0] + red2[1] + red2[2] + red2[3]) * (1.f / 512.f);
  float rstd = 1.f / sqrtf(var + 1e-5f);
  float y0 = d0 * rstd * sg[t] + bg[t];
  float y1 = d1 * rstd * sg[t + 256] + bg[t + 256];
  outf[base + t] = y0; outf[base + t + 256] = y1;
  outb[base + t] = f2bf(y0); outb[base + t + 256] = f2bf(y1);
}

// ---------------- weight fp32 (K,N) -> bf16 transposed (N,K) ----------------
__global__ __launch_bounds__(256) void wconv_kernel(const float* __restrict__ w,
    unsigned short* __restrict__ wt, int K, int N, size_t sStride, size_t dStride)
{
  __shared__ float tile[32][33];
  const float* wl = w + blockIdx.z * sStride;
  unsigned short* wtl = wt + blockIdx.z * dStride;
  int n0 = blockIdx.x * 32, k0 = blockIdx.y * 32;
  int c = threadIdx.x & 31, r8 = threadIdx.x >> 5;
  #pragma unroll
  for (int p = 0; p < 4; p++){ int r = r8 + p * 8; tile[r][c] = wl[(size_t)(k0 + r) * N + n0 + c]; }
  __syncthreads();
  #pragma unroll
  for (int p = 0; p < 4; p++){ int r = r8 + p * 8; wtl[(size_t)(n0 + r) * K + k0 + c] = f2bf(tile[c][r]); }
}

// ---------------- bf16 MFMA GEMM: C(M,N) = A(M,K) * Wt(N,K)^T ----------------
// EPI: 0 = +residual -> f32, 1 = bf16 store, 2 = bias+gelu -> bf16, 3 = bias+residual -> f32
template<int EPI>
__global__ __launch_bounds__(256) void gemm_kernel(
    const unsigned short* __restrict__ A, const unsigned short* __restrict__ Wt,
    float* __restrict__ Cf, unsigned short* __restrict__ Cb,
    const float* __restrict__ bias, const float* __restrict__ Rf, int N, int K)
{
  __shared__ __align__(16) unsigned short As[128 * 32];
  __shared__ __align__(16) unsigned short Bs[128 * 32];
  const int tid = threadIdx.x;
  const int wv = tid >> 6, lane = tid & 63;
  const int m0 = blockIdx.x * 128, n0 = blockIdx.y * 128;
  const int wm = (wv >> 1) * 64, wn = (wv & 1) * 64;
  const int r16 = lane & 15, g = lane >> 4;

  const unsigned short* gA = A + (size_t)(m0 + 32 * wv + (lane >> 2)) * K + (lane & 3) * 8;
  const unsigned short* gB = Wt + (size_t)(n0 + 32 * wv + (lane >> 2)) * K + (lane & 3) * 8;
  unsigned short* lA = As + wv * 1024;
  unsigned short* lB = Bs + wv * 1024;

  f32x4 acc[4][4] = {};

  for (int k0 = 0; k0 < K; k0 += 32){
    GLD_LDS16(gA + k0,          lA);
    GLD_LDS16(gA + k0 + 16 * K, lA + 512);
    GLD_LDS16(gB + k0,          lB);
    GLD_LDS16(gB + k0 + 16 * K, lB + 512);
    __syncthreads();
    bf16x8 av[4], bv[4];
    #pragma unroll
    for (int m = 0; m < 4; m++)
      av[m] = *reinterpret_cast<const bf16x8*>(&As[((wm + m * 16 + r16) * 4 + g) * 8]);
    #pragma unroll
    for (int n = 0; n < 4; n++)
      bv[n] = *reinterpret_cast<const bf16x8*>(&Bs[((wn + n * 16 + r16) * 4 + g) * 8]);
    #pragma unroll
    for (int m = 0; m < 4; m++)
      #pragma unroll
      for (int n = 0; n < 4; n++)
        acc[m][n] = __builtin_amdgcn_mfma_f32_16x16x32_bf16(av[m], bv[n], acc[m][n], 0, 0, 0);
    __syncthreads();
  }

  const int colBase = n0 + wn + r16;
  #pragma unroll
  for (int m = 0; m < 4; m++){
    int rowBase = m0 + wm + m * 16 + g * 4;
    #pragma unroll
    for (int n = 0; n < 4; n++){
      int col = colBase + n * 16;
      float bsv = (EPI >= 2) ? bias[col] : 0.f;
      #pragma unroll
      for (int j = 0; j < 4; j++){
        float vlu = acc[m][n][j];
        if (EPI >= 2) vlu += bsv;
        if (EPI == 2) vlu = 0.5f * vlu * (1.f + erff(vlu * 0.70710678118654752f));
        size_t off = (size_t)(rowBase + j) * N + col;
        if (EPI == 0 || EPI == 3) vlu += Rf[off];
        if (EPI == 1 || EPI == 2) Cb[off] = f2bf(vlu);
        else                      Cf[off] = vlu;
      }
    }
  }
}

// ---------------- sparse tree attention: one wave per (b,n,h) ----------------
__global__ __launch_bounds__(256) void attn_kernel(
    const unsigned short* __restrict__ qkv, unsigned short* __restrict__ ctx)
{
  int wid = blockIdx.x * 4 + (threadIdx.x >> 6);
  int lane = threadIdx.x & 63;
  int h = wid & 7;
  int tmp = wid >> 3;
  int n = tmp % NTOT_C;
  int b = tmp / NTOT_C;

  int i, sz, of, cb, par;
  if (n < 1024){ i = n;        sz = 1024; of = 0;    cb = -1;            par = 1024 + (i >> 2); }
  else if (n < 1280){ i = n - 1024; sz = 256; of = 1024; cb = 0    + 4 * i; par = 1280 + (i >> 2); }
  else if (n < 1344){ i = n - 1280; sz = 64;  of = 1280; cb = 1024 + 4 * i; par = 1344 + (i >> 2); }
  else if (n < 1360){ i = n - 1344; sz = 16;  of = 1344; cb = 1280 + 4 * i; par = 1360 + (i >> 2); }
  else if (n < 1364){ i = n - 1360; sz = 4;   of = 1360; cb = 1344 + 4 * i; par = 1364; }
  else { i = 0; sz = 1; of = 1364; cb = 1360; par = -1; }

  int nb[10];
  #pragma unroll
  for (int s5 = 0; s5 < 5; s5++){ int pos = i - 2 + s5; nb[s5] = (pos >= 0 && pos < sz) ? of + pos : -1; }
  #pragma unroll
  for (int r = 0; r < 4; r++) nb[5 + r] = (cb >= 0) ? cb + r : -1;
  nb[9] = par;

  size_t rowBase = ((size_t)b * NTOT_C) * 1536;
  float qd = bf2f(qkv[rowBase + (size_t)n * 1536 + h * 64 + lane]);

  float sc[10];
  #pragma unroll
  for (int j = 0; j < 10; j++){
    int id = nb[j] >= 0 ? nb[j] : n;
    float kd = bf2f(qkv[rowBase + (size_t)id * 1536 + 512 + h * 64 + lane]);
    float p = qd * kd;
    #pragma unroll
    for (int o = 32; o; o >>= 1) p += __shfl_xor(p, o, 64);
    sc[j] = (nb[j] >= 0) ? p * 0.125f : -1e30f;
  }
  float mx = sc[0];
  #pragma unroll
  for (int j = 1; j < 10; j++) mx = fmaxf(mx, sc[j]);
  float den = 0.f, accv = 0.f;
  #pragma unroll
  for (int j = 0; j < 10; j++){
    float wj = (nb[j] >= 0) ? expf(sc[j] - mx) : 0.f;
    den += wj;
    int id = nb[j] >= 0 ? nb[j] : n;
    float vd = bf2f(qkv[rowBase + (size_t)id * 1536 + 1024 + h * 64 + lane]);
    accv += wj * vd;
  }
  ctx[((size_t)b * NTOT_C + n) * 512 + h * 64 + lane] = f2bf(accv / den);
}

// ---------------- gather effective prefixes -> output ----------------
__global__ __launch_bounds__(256) void gather_kernel(const float* __restrict__ seqf,
    float* __restrict__ out)
{
  int e = blockIdx.x * 256 + threadIdx.x;
  int d = e & 511;
  int r = e >> 9;
  int j = r % 1334;
  int b = r / 1334;
  int src;
  if      (j < 1000) src = j;
  else if (j < 1250) src = j + 24;
  else if (j < 1313) src = j + 30;
  else if (j < 1333) src = j + 31;
  else               src = 1364;
  out[e] = seqf[((size_t)b * NTOT_C + src) * 512 + d];
}

extern "C" void kernel_launch(void* const* d_in, const int* in_sizes, int n_in,
                              void* d_out, int out_size, void* d_ws, size_t ws_size,
                              hipStream_t stream)
{
  const float* x      = (const float*)d_in[0];
  const float* conv_w = (const float*)d_in[1];
  const float* norm_s = (const float*)d_in[2];
  const float* norm_b = (const float*)d_in[3];
  const float* wq     = (const float*)d_in[4];
  const float* wk     = (const float*)d_in[5];
  const float* wv     = (const float*)d_in[6];
  const float* wo     = (const float*)d_in[7];
  const float* ln1_s  = (const float*)d_in[8];
  const float* ln1_b  = (const float*)d_in[9];
  const float* w1     = (const float*)d_in[10];
  const float* b1     = (const float*)d_in[11];
  const float* w2     = (const float*)d_in[12];
  const float* b2     = (const float*)d_in[13];
  const float* ln2_s  = (const float*)d_in[14];
  const float* ln2_b  = (const float*)d_in[15];
  float* out = (float*)d_out;

  char* ws = (char*)d_ws;
  size_t off = 0;
  auto alloc = [&](size_t bytes) -> char* {
    char* p = ws + off; off += (bytes + 255) & ~(size_t)255; return p;
  };
  unsigned short* qkvT = (unsigned short*)alloc((size_t)NLAY * 1536 * 512 * 2);
  unsigned short* woT  = (unsigned short*)alloc((size_t)NLAY * 512 * 512 * 2);
  unsigned short* w1T  = (unsigned short*)alloc((size_t)NLAY * 2048 * 512 * 2);
  unsigned short* w2T  = (unsigned short*)alloc((size_t)NLAY * 512 * 2048 * 2);
  float*          seqf = (float*)alloc((size_t)M_PAD * 512 * 4);
  unsigned short* seqb = (unsigned short*)alloc((size_t)M_PAD * 512 * 2);
  float*          buff = (float*)alloc((size_t)M_PAD * 512 * 4);
  unsigned short* qkvb = (unsigned short*)alloc((size_t)M_PAD * 1536 * 2);
  unsigned short* ctxb = (unsigned short*)alloc((size_t)M_PAD * 512 * 2);
  unsigned short* ffn1 = qkvb;  // alias: ffn1 (M_PAD x 2048) == qkvb + ctxb region
  float*          pe   = buff;  // alias: PE table (SEQN x 512 f32) lives in buff pre-loop

  // weight transforms (per launch; cheap)
  wconv_kernel<<<dim3(16,16,NLAY),256,0,stream>>>(wq, qkvT,              512,  512,  (size_t)512*512,  (size_t)1536*512);
  wconv_kernel<<<dim3(16,16,NLAY),256,0,stream>>>(wk, qkvT + 512*512,    512,  512,  (size_t)512*512,  (size_t)1536*512);
  wconv_kernel<<<dim3(16,16,NLAY),256,0,stream>>>(wv, qkvT + 1024*512,   512,  512,  (size_t)512*512,  (size_t)1536*512);
  wconv_kernel<<<dim3(16,16,NLAY),256,0,stream>>>(wo, woT,               512,  512,  (size_t)512*512,  (size_t)512*512);
  wconv_kernel<<<dim3(64,16,NLAY),256,0,stream>>>(w1, w1T,               512,  2048, (size_t)512*2048, (size_t)512*2048);
  wconv_kernel<<<dim3(16,64,NLAY),256,0,stream>>>(w2, w2T,               2048, 512,  (size_t)2048*512, (size_t)2048*512);

  // embedding + pyramid
  pe_kernel<<<(SEQN * 512) / 256, 256, 0, stream>>>(pe);
  conv_kernel<<<dim3(4,16,BQ), 256, 0, stream>>>(x, conv_w, pe, seqf);
  const int psz[6]  = {1024, 256, 64, 16, 4, 1};
  const int poff[6] = {0, 1024, 1280, 1344, 1360, 1364};
  for (int l = 0; l < 5; l++)
    pool_kernel<<<(BQ * psz[l+1] * 512) / 256, 256, 0, stream>>>(seqf, poff[l], poff[l+1], psz[l+1]);
  ln_kernel<false><<<M_PAD, 256, 0, stream>>>(seqf, nullptr, seqf, seqb, norm_s, norm_b, M_REAL);

  for (int l = 0; l < NLAY; l++){
    gemm_kernel<1><<<dim3(86,12),256,0,stream>>>(seqb, qkvT + (size_t)l*1536*512, nullptr, qkvb, nullptr, nullptr, 1536, 512);
    attn_kernel<<<(BQ * NTOT_C * NH) / 4, 256, 0, stream>>>(qkvb, ctxb);
    // WO GEMM: ctx @ wo + seq(residual) -> buff (f32)
    gemm_kernel<0><<<dim3(86,4),256,0,stream>>>(ctxb, woT + (size_t)l*512*512, buff, nullptr, nullptr, seqf, 512, 512);
    ln_kernel<false><<<M_PAD,256,0,stream>>>(buff, nullptr, seqf, seqb, ln1_s + l*512, ln1_b + l*512, M_REAL);
    gemm_kernel<2><<<dim3(86,16),256,0,stream>>>(seqb, w1T + (size_t)l*2048*512, nullptr, ffn1, b1 + l*2048, nullptr, 2048, 512);
    // FFN2 GEMM: ffn1 @ w2 + b2 + seq(residual) -> buff (f32)
    gemm_kernel<3><<<dim3(86,4),256,0,stream>>>(ffn1, w2T + (size_t)l*512*2048, buff, nullptr, b2 + l*512, seqf, 512, 2048);
    ln_kernel<false><<<M_PAD,256,0,stream>>>(buff, nullptr, seqf, seqb, ln2_s + l*512, ln2_b + l*512, M_REAL);
  }

  gather_kernel<<<(BQ * 1334 * 512) / 256, 256, 0, stream>>>(seqf, out);
}

// Round 4
// 891.782 us; speedup vs baseline: 1.3290x; 1.1594x over previous
//
#include <hip/hip_runtime.h>
#include <cstdint>
#include <math.h>

#define DEV __device__ __forceinline__

static constexpr int BQ = 8, SEQN = 1000, CIN = 32, NH = 8;
static constexpr int NLAY = 4;
static constexpr int NTOT_C = 1365;
static constexpr int M_REAL = BQ * NTOT_C;   // 10920
static constexpr int M_PAD  = 11008;         // 86 * 128

DEV float bf2f(unsigned short u){ return __uint_as_float(((unsigned)u) << 16); }
DEV unsigned short f2bf(float f){
  unsigned u = __float_as_uint(f);
  u += 0x7fffu + ((u >> 16) & 1u);
  return (unsigned short)(u >> 16);
}

typedef __bf16 bf16x8 __attribute__((ext_vector_type(8)));
typedef float  f32x4  __attribute__((ext_vector_type(4)));
typedef unsigned short u16x8 __attribute__((ext_vector_type(8)));

#define GLD_LDS16(gp, lp) __builtin_amdgcn_global_load_lds( \
    (const __attribute__((address_space(1))) void*)(gp), \
    (__attribute__((address_space(3))) void*)(lp), 16, 0, 0)

// ---------------- sinusoid PE table (fp32), SEQN x 512 ----------------
__global__ __launch_bounds__(256) void pe_kernel(float* __restrict__ pe)
{
  int idx = blockIdx.x * 256 + threadIdx.x;   // [0, SEQN*512)
  int d = idx & 511, s = idx >> 9;
  if (s >= SEQN) return;
  float e2 = (float)(d & ~1);
  float freq = exp2f(e2 * (-13.287712379549449f / 512.0f));
  float ang = (float)s * freq;
  pe[idx] = (d & 1) ? cosf(ang) : sinf(ang);
}

// ---------------- conv1d (k=3 circular), tiled: 64 s x 128 d per block ----------------
__global__ __launch_bounds__(256) void conv_kernel(const float* __restrict__ x,
    const float* __restrict__ w, const float* __restrict__ pe, float* __restrict__ seqf)
{
  __shared__ float ws_w[128 * 97];
  __shared__ __align__(16) float xs[66][32];
  int b = blockIdx.z, s0 = blockIdx.y * 64, d0 = blockIdx.x * 128;
  int tid = threadIdx.x;
  for (int i = tid; i < 128 * 96; i += 256){
    int r = i / 96, c = i - r * 96;
    ws_w[r * 97 + c] = w[(size_t)(d0 + r) * 96 + c];
  }
  for (int i = tid; i < 66 * 32; i += 256){
    int r = i >> 5, c = i & 31;
    int ss = s0 + r - 1;
    ss = (ss < 0) ? (ss + SEQN) : (ss >= SEQN ? ss - SEQN : ss);
    xs[r][c] = x[((size_t)b * SEQN + ss) * CIN + c];
  }
  __syncthreads();
  int dl = tid & 127, sh = tid >> 7;
  float wr[96];
  #pragma unroll
  for (int i = 0; i < 96; i++) wr[i] = ws_w[dl * 97 + i];
  int d = d0 + dl;
  for (int si = 0; si < 32; si++){
    int sl = sh * 32 + si;
    int s = s0 + sl;
    float acc = 0.f;
    #pragma unroll
    for (int kk = 0; kk < 3; kk++){
      const float* xr = xs[sl + kk];
      #pragma unroll
      for (int c = 0; c < 32; c++) acc += xr[c] * wr[c * 3 + kk];
    }
    float outv = (s < SEQN) ? acc + pe[(size_t)s * 512 + d] : 0.f;
    seqf[((size_t)b * NTOT_C + s) * 512 + d] = outv;
  }
}

// ---------------- max-pool one pyramid level ----------------
__global__ __launch_bounds__(256) void pool_kernel(float* __restrict__ seqf,
    int inOff, int outOff, int outSz)
{
  int e = blockIdx.x * 256 + threadIdx.x;
  int d = e & 511;
  int r = e >> 9;
  int i = r % outSz;
  int b = r / outSz;
  const float* src = seqf + ((size_t)b * NTOT_C + inOff + 4 * i) * 512 + d;
  float m = fmaxf(fmaxf(src[0], src[512]), fmaxf(src[1024], src[1536]));
  seqf[((size_t)b * NTOT_C + outOff + i) * 512 + d] = m;
}

// ---------------- LayerNorm, emits fp32 + bf16 ----------------
template<bool RES>
__global__ __launch_bounds__(256) void ln_kernel(const float* __restrict__ xin,
    const float* __restrict__ rin, float* __restrict__ outf, unsigned short* __restrict__ outb,
    const float* __restrict__ sg, const float* __restrict__ bg, int M)
{
  int row = blockIdx.x;
  int t = threadIdx.x;
  size_t base = (size_t)row * 512;
  if (row >= M){ outb[base + t] = 0; outb[base + t + 256] = 0; return; }
  float v0 = xin[base + t], v1 = xin[base + t + 256];
  if (RES){ v0 += rin[base + t]; v1 += rin[base + t + 256]; }
  __shared__ float red1[4], red2[4];
  int wv = t >> 6;
  float sall = v0 + v1;
  #pragma unroll
  for (int o = 32; o; o >>= 1) sall += __shfl_xor(sall, o, 64);
  if ((t & 63) == 0) red1[wv] = sall;
  __syncthreads();
  float mean = (red1[0] + red1[1] + red1[2] + red1[3]) * (1.f / 512.f);
  float d0 = v0 - mean, d1 = v1 - mean;
  float sq = d0 * d0 + d1 * d1;
  #pragma unroll
  for (int o = 32; o; o >>= 1) sq += __shfl_xor(sq, o, 64);
  if ((t & 63) == 0) red2[wv] = sq;
  __syncthreads();
  float var = (red2[0] + red2[1] + red2[2] + red2[3]) * (1.f / 512.f);
  float rstd = 1.f / sqrtf(var + 1e-5f);
  float y0 = d0 * rstd * sg[t] + bg[t];
  float y1 = d1 * rstd * sg[t + 256] + bg[t + 256];
  outf[base + t] = y0; outf[base + t + 256] = y1;
  outb[base + t] = f2bf(y0); outb[base + t + 256] = f2bf(y1);
}

// ---------------- weight fp32 (K,N) -> bf16 transposed (N,K) ----------------
__global__ __launch_bounds__(256) void wconv_kernel(const float* __restrict__ w,
    unsigned short* __restrict__ wt, int K, int N, size_t sStride, size_t dStride)
{
  __shared__ float tile[32][33];
  const float* wl = w + blockIdx.z * sStride;
  unsigned short* wtl = wt + blockIdx.z * dStride;
  int n0 = blockIdx.x * 32, k0 = blockIdx.y * 32;
  int c = threadIdx.x & 31, r8 = threadIdx.x >> 5;
  #pragma unroll
  for (int p = 0; p < 4; p++){ int r = r8 + p * 8; tile[r][c] = wl[(size_t)(k0 + r) * N + n0 + c]; }
  __syncthreads();
  #pragma unroll
  for (int p = 0; p < 4; p++){ int r = r8 + p * 8; wtl[(size_t)(n0 + r) * K + k0 + c] = f2bf(tile[c][r]); }
}

// ---------------- bf16 MFMA GEMM: C(M,N) = A(M,K) * Wt(N,K)^T ----------------
// EPI: 0 = +residual -> f32, 1 = bf16 store, 2 = bias+gelu -> bf16, 3 = bias+residual -> f32
template<int EPI>
__global__ __launch_bounds__(256) void gemm_kernel(
    const unsigned short* __restrict__ A, const unsigned short* __restrict__ Wt,
    float* __restrict__ Cf, unsigned short* __restrict__ Cb,
    const float* __restrict__ bias, const float* __restrict__ Rf, int N, int K)
{
  __shared__ __align__(16) unsigned short As[128 * 32];
  __shared__ __align__(16) unsigned short Bs[128 * 32];
  const int tid = threadIdx.x;
  const int wv = tid >> 6, lane = tid & 63;
  const int m0 = blockIdx.x * 128, n0 = blockIdx.y * 128;
  const int wm = (wv >> 1) * 64, wn = (wv & 1) * 64;
  const int r16 = lane & 15, g = lane >> 4;

  const unsigned short* gA = A + (size_t)(m0 + 32 * wv + (lane >> 2)) * K + (lane & 3) * 8;
  const unsigned short* gB = Wt + (size_t)(n0 + 32 * wv + (lane >> 2)) * K + (lane & 3) * 8;
  unsigned short* lA = As + wv * 1024;
  unsigned short* lB = Bs + wv * 1024;

  f32x4 acc[4][4] = {};

  for (int k0 = 0; k0 < K; k0 += 32){
    GLD_LDS16(gA + k0,          lA);
    GLD_LDS16(gA + k0 + 16 * K, lA + 512);
    GLD_LDS16(gB + k0,          lB);
    GLD_LDS16(gB + k0 + 16 * K, lB + 512);
    __syncthreads();
    bf16x8 av[4], bv[4];
    #pragma unroll
    for (int m = 0; m < 4; m++)
      av[m] = *reinterpret_cast<const bf16x8*>(&As[((wm + m * 16 + r16) * 4 + g) * 8]);
    #pragma unroll
    for (int n = 0; n < 4; n++)
      bv[n] = *reinterpret_cast<const bf16x8*>(&Bs[((wn + n * 16 + r16) * 4 + g) * 8]);
    #pragma unroll
    for (int m = 0; m < 4; m++)
      #pragma unroll
      for (int n = 0; n < 4; n++)
        acc[m][n] = __builtin_amdgcn_mfma_f32_16x16x32_bf16(av[m], bv[n], acc[m][n], 0, 0, 0);
    __syncthreads();
  }

  const int colBase = n0 + wn + r16;
  #pragma unroll
  for (int m = 0; m < 4; m++){
    int rowBase = m0 + wm + m * 16 + g * 4;
    #pragma unroll
    for (int n = 0; n < 4; n++){
      int col = colBase + n * 16;
      float bsv = (EPI >= 2) ? bias[col] : 0.f;
      #pragma unroll
      for (int j = 0; j < 4; j++){
        float vlu = acc[m][n][j];
        if (EPI >= 2) vlu += bsv;
        if (EPI == 2) vlu = 0.5f * vlu * (1.f + erff(vlu * 0.70710678118654752f));
        size_t off = (size_t)(rowBase + j) * N + col;
        if (EPI == 0 || EPI == 3) vlu += Rf[off];
        if (EPI == 1 || EPI == 2) Cb[off] = f2bf(vlu);
        else                      Cf[off] = vlu;
      }
    }
  }
}

// ---------------- sparse tree attention: one wave per (b,n), all 8 heads ----------------
// lane l owns row elements [8l, 8l+8) = head (l>>3), d-slice 8*(l&7)..
__global__ __launch_bounds__(256) void attn_kernel(
    const unsigned short* __restrict__ qkv, unsigned short* __restrict__ ctx)
{
  int wid = blockIdx.x * 4 + (threadIdx.x >> 6);
  int lane = threadIdx.x & 63;
  int n = wid % NTOT_C;
  int b = wid / NTOT_C;

  int i, sz, of, cb, par;
  if (n < 1024){ i = n;        sz = 1024; of = 0;    cb = -1;            par = 1024 + (i >> 2); }
  else if (n < 1280){ i = n - 1024; sz = 256; of = 1024; cb = 0    + 4 * i; par = 1280 + (i >> 2); }
  else if (n < 1344){ i = n - 1280; sz = 64;  of = 1280; cb = 1024 + 4 * i; par = 1344 + (i >> 2); }
  else if (n < 1360){ i = n - 1344; sz = 16;  of = 1344; cb = 1280 + 4 * i; par = 1360 + (i >> 2); }
  else if (n < 1364){ i = n - 1360; sz = 4;   of = 1360; cb = 1344 + 4 * i; par = 1364; }
  else { i = 0; sz = 1; of = 1364; cb = 1360; par = -1; }

  int nb[10];
  #pragma unroll
  for (int s5 = 0; s5 < 5; s5++){ int pos = i - 2 + s5; nb[s5] = (pos >= 0 && pos < sz) ? of + pos : -1; }
  #pragma unroll
  for (int r = 0; r < 4; r++) nb[5 + r] = (cb >= 0) ? cb + r : -1;
  nb[9] = par;

  const unsigned short* rows = qkv + ((size_t)b * NTOT_C) * 1536;

  u16x8 qv = *reinterpret_cast<const u16x8*>(rows + (size_t)n * 1536 + lane * 8);
  float qf[8];
  #pragma unroll
  for (int e = 0; e < 8; e++) qf[e] = bf2f(qv[e]);

  float sc[10];
  #pragma unroll
  for (int j = 0; j < 10; j++){
    int id = nb[j] >= 0 ? nb[j] : n;
    u16x8 kv = *reinterpret_cast<const u16x8*>(rows + (size_t)id * 1536 + 512 + lane * 8);
    float p = 0.f;
    #pragma unroll
    for (int e = 0; e < 8; e++) p += qf[e] * bf2f(kv[e]);
    // reduce within 8-lane head group (butterfly -> all lanes hold head dot)
    p += __shfl_xor(p, 1, 64);
    p += __shfl_xor(p, 2, 64);
    p += __shfl_xor(p, 4, 64);
    sc[j] = (nb[j] >= 0) ? p * 0.125f : -1e30f;
  }
  float mx = sc[0];
  #pragma unroll
  for (int j = 1; j < 10; j++) mx = fmaxf(mx, sc[j]);
  float den = 0.f;
  float wj[10];
  #pragma unroll
  for (int j = 0; j < 10; j++){
    wj[j] = (nb[j] >= 0) ? expf(sc[j] - mx) : 0.f;
    den += wj[j];
  }
  float rden = 1.f / den;
  float accv[8] = {};
  #pragma unroll
  for (int j = 0; j < 10; j++){
    int id = nb[j] >= 0 ? nb[j] : n;
    u16x8 vv = *reinterpret_cast<const u16x8*>(rows + (size_t)id * 1536 + 1024 + lane * 8);
    float w = wj[j];
    #pragma unroll
    for (int e = 0; e < 8; e++) accv[e] += w * bf2f(vv[e]);
  }
  u16x8 ov;
  #pragma unroll
  for (int e = 0; e < 8; e++) ov[e] = f2bf(accv[e] * rden);
  *reinterpret_cast<u16x8*>(ctx + ((size_t)b * NTOT_C + n) * 512 + lane * 8) = ov;
}

// ---------------- gather effective prefixes -> output ----------------
__global__ __launch_bounds__(256) void gather_kernel(const float* __restrict__ seqf,
    float* __restrict__ out)
{
  int e = blockIdx.x * 256 + threadIdx.x;
  int d = e & 511;
  int r = e >> 9;
  int j = r % 1334;
  int b = r / 1334;
  int src;
  if      (j < 1000) src = j;
  else if (j < 1250) src = j + 24;
  else if (j < 1313) src = j + 30;
  else if (j < 1333) src = j + 31;
  else               src = 1364;
  out[e] = seqf[((size_t)b * NTOT_C + src) * 512 + d];
}

extern "C" void kernel_launch(void* const* d_in, const int* in_sizes, int n_in,
                              void* d_out, int out_size, void* d_ws, size_t ws_size,
                              hipStream_t stream)
{
  const float* x      = (const float*)d_in[0];
  const float* conv_w = (const float*)d_in[1];
  const float* norm_s = (const float*)d_in[2];
  const float* norm_b = (const float*)d_in[3];
  const float* wq     = (const float*)d_in[4];
  const float* wk     = (const float*)d_in[5];
  const float* wv     = (const float*)d_in[6];
  const float* wo     = (const float*)d_in[7];
  const float* ln1_s  = (const float*)d_in[8];
  const float* ln1_b  = (const float*)d_in[9];
  const float* w1     = (const float*)d_in[10];
  const float* b1     = (const float*)d_in[11];
  const float* w2     = (const float*)d_in[12];
  const float* b2     = (const float*)d_in[13];
  const float* ln2_s  = (const float*)d_in[14];
  const float* ln2_b  = (const float*)d_in[15];
  float* out = (float*)d_out;

  char* ws = (char*)d_ws;
  size_t off = 0;
  auto alloc = [&](size_t bytes) -> char* {
    char* p = ws + off; off += (bytes + 255) & ~(size_t)255; return p;
  };
  unsigned short* qkvT = (unsigned short*)alloc((size_t)NLAY * 1536 * 512 * 2);
  unsigned short* woT  = (unsigned short*)alloc((size_t)NLAY * 512 * 512 * 2);
  unsigned short* w1T  = (unsigned short*)alloc((size_t)NLAY * 2048 * 512 * 2);
  unsigned short* w2T  = (unsigned short*)alloc((size_t)NLAY * 512 * 2048 * 2);
  float*          seqf = (float*)alloc((size_t)M_PAD * 512 * 4);
  unsigned short* seqb = (unsigned short*)alloc((size_t)M_PAD * 512 * 2);
  float*          buff = (float*)alloc((size_t)M_PAD * 512 * 4);
  unsigned short* qkvb = (unsigned short*)alloc((size_t)M_PAD * 1536 * 2);
  unsigned short* ctxb = (unsigned short*)alloc((size_t)M_PAD * 512 * 2);
  unsigned short* ffn1 = qkvb;  // alias
  float*          pe   = buff;  // alias: PE table pre-loop

  wconv_kernel<<<dim3(16,16,NLAY),256,0,stream>>>(wq, qkvT,              512,  512,  (size_t)512*512,  (size_t)1536*512);
  wconv_kernel<<<dim3(16,16,NLAY),256,0,stream>>>(wk, qkvT + 512*512,    512,  512,  (size_t)512*512,  (size_t)1536*512);
  wconv_kernel<<<dim3(16,16,NLAY),256,0,stream>>>(wv, qkvT + 1024*512,   512,  512,  (size_t)512*512,  (size_t)1536*512);
  wconv_kernel<<<dim3(16,16,NLAY),256,0,stream>>>(wo, woT,               512,  512,  (size_t)512*512,  (size_t)512*512);
  wconv_kernel<<<dim3(64,16,NLAY),256,0,stream>>>(w1, w1T,               512,  2048, (size_t)512*2048, (size_t)512*2048);
  wconv_kernel<<<dim3(16,64,NLAY),256,0,stream>>>(w2, w2T,               2048, 512,  (size_t)2048*512, (size_t)2048*512);

  pe_kernel<<<(SEQN * 512) / 256, 256, 0, stream>>>(pe);
  conv_kernel<<<dim3(4,16,BQ), 256, 0, stream>>>(x, conv_w, pe, seqf);
  const int psz[6]  = {1024, 256, 64, 16, 4, 1};
  const int poff[6] = {0, 1024, 1280, 1344, 1360, 1364};
  for (int l = 0; l < 5; l++)
    pool_kernel<<<(BQ * psz[l+1] * 512) / 256, 256, 0, stream>>>(seqf, poff[l], poff[l+1], psz[l+1]);
  ln_kernel<false><<<M_PAD, 256, 0, stream>>>(seqf, nullptr, seqf, seqb, norm_s, norm_b, M_REAL);

  for (int l = 0; l < NLAY; l++){
    gemm_kernel<1><<<dim3(86,12),256,0,stream>>>(seqb, qkvT + (size_t)l*1536*512, nullptr, qkvb, nullptr, nullptr, 1536, 512);
    attn_kernel<<<(BQ * NTOT_C + 3) / 4, 256, 0, stream>>>(qkvb, ctxb);
    gemm_kernel<0><<<dim3(86,4),256,0,stream>>>(ctxb, woT + (size_t)l*512*512, buff, nullptr, nullptr, seqf, 512, 512);
    ln_kernel<false><<<M_PAD,256,0,stream>>>(buff, nullptr, seqf, seqb, ln1_s + l*512, ln1_b + l*512, M_REAL);
    gemm_kernel<2><<<dim3(86,16),256,0,stream>>>(seqb, w1T + (size_t)l*2048*512, nullptr, ffn1, b1 + l*2048, nullptr, 2048, 512);
    gemm_kernel<3><<<dim3(86,4),256,0,stream>>>(ffn1, w2T + (size_t)l*512*2048, buff, nullptr, b2 + l*512, seqf, 512, 2048);
    ln_kernel<false><<<M_PAD,256,0,stream>>>(buff, nullptr, seqf, seqb, ln2_s + l*512, ln2_b + l*512, M_REAL);
  }

  gather_kernel<<<(BQ * 1334 * 512) / 256, 256, 0, stream>>>(seqf, out);
}

// Round 5
// 843.711 us; speedup vs baseline: 1.4047x; 1.0570x over previous
//
#include <hip/hip_runtime.h>
#include <cstdint>
#include <math.h>

#define DEV __device__ __forceinline__

static constexpr int BQ = 8, SEQN = 1000, CIN = 32, NH = 8;
static constexpr int NLAY = 4;
static constexpr int NTOT_C = 1365;
static constexpr int M_REAL = BQ * NTOT_C;   // 10920
static constexpr int M_PAD  = 11008;         // 86 * 128 = 172 * 64

DEV float bf2f(unsigned short u){ return __uint_as_float(((unsigned)u) << 16); }
DEV unsigned short f2bf(float f){
  unsigned u = __float_as_uint(f);
  u += 0x7fffu + ((u >> 16) & 1u);
  return (unsigned short)(u >> 16);
}

typedef __bf16 bf16x8 __attribute__((ext_vector_type(8)));
typedef float  f32x4  __attribute__((ext_vector_type(4)));
typedef unsigned short u16x8 __attribute__((ext_vector_type(8)));

#define GLD_LDS16(gp, lp) __builtin_amdgcn_global_load_lds( \
    (const __attribute__((address_space(1))) void*)(gp), \
    (__attribute__((address_space(3))) void*)(lp), 16, 0, 0)

// ---------------- sinusoid PE table (fp32), SEQN x 512 ----------------
__global__ __launch_bounds__(256) void pe_kernel(float* __restrict__ pe)
{
  int idx = blockIdx.x * 256 + threadIdx.x;
  int d = idx & 511, s = idx >> 9;
  if (s >= SEQN) return;
  float e2 = (float)(d & ~1);
  float freq = exp2f(e2 * (-13.287712379549449f / 512.0f));
  float ang = (float)s * freq;
  pe[idx] = (d & 1) ? cosf(ang) : sinf(ang);
}

// ---------------- conv1d (k=3 circular), tiled: 64 s x 128 d per block ----------------
__global__ __launch_bounds__(256) void conv_kernel(const float* __restrict__ x,
    const float* __restrict__ w, const float* __restrict__ pe, float* __restrict__ seqf)
{
  __shared__ float ws_w[128 * 97];
  __shared__ __align__(16) float xs[66][32];
  int b = blockIdx.z, s0 = blockIdx.y * 64, d0 = blockIdx.x * 128;
  int tid = threadIdx.x;
  for (int i = tid; i < 128 * 96; i += 256){
    int r = i / 96, c = i - r * 96;
    ws_w[r * 97 + c] = w[(size_t)(d0 + r) * 96 + c];
  }
  for (int i = tid; i < 66 * 32; i += 256){
    int r = i >> 5, c = i & 31;
    int ss = s0 + r - 1;
    ss = (ss < 0) ? (ss + SEQN) : (ss >= SEQN ? ss - SEQN : ss);
    xs[r][c] = x[((size_t)b * SEQN + ss) * CIN + c];
  }
  __syncthreads();
  int dl = tid & 127, sh = tid >> 7;
  float wr[96];
  #pragma unroll
  for (int i = 0; i < 96; i++) wr[i] = ws_w[dl * 97 + i];
  int d = d0 + dl;
  for (int si = 0; si < 32; si++){
    int sl = sh * 32 + si;
    int s = s0 + sl;
    float acc = 0.f;
    #pragma unroll
    for (int kk = 0; kk < 3; kk++){
      const float* xr = xs[sl + kk];
      #pragma unroll
      for (int c = 0; c < 32; c++) acc += xr[c] * wr[c * 3 + kk];
    }
    float outv = (s < SEQN) ? acc + pe[(size_t)s * 512 + d] : 0.f;
    seqf[((size_t)b * NTOT_C + s) * 512 + d] = outv;
  }
}

// ---------------- max-pool one pyramid level ----------------
__global__ __launch_bounds__(256) void pool_kernel(float* __restrict__ seqf,
    int inOff, int outOff, int outSz)
{
  int e = blockIdx.x * 256 + threadIdx.x;
  int d = e & 511;
  int r = e >> 9;
  int i = r % outSz;
  int b = r / outSz;
  const float* src = seqf + ((size_t)b * NTOT_C + inOff + 4 * i) * 512 + d;
  float m = fmaxf(fmaxf(src[0], src[512]), fmaxf(src[1024], src[1536]));
  seqf[((size_t)b * NTOT_C + outOff + i) * 512 + d] = m;
}

// ---------------- LayerNorm, emits fp32 + bf16 ----------------
template<bool RES>
__global__ __launch_bounds__(256) void ln_kernel(const float* __restrict__ xin,
    const float* __restrict__ rin, float* __restrict__ outf, unsigned short* __restrict__ outb,
    const float* __restrict__ sg, const float* __restrict__ bg, int M)
{
  int row = blockIdx.x;
  int t = threadIdx.x;
  size_t base = (size_t)row * 512;
  if (row >= M){ outb[base + t] = 0; outb[base + t + 256] = 0; return; }
  float v0 = xin[base + t], v1 = xin[base + t + 256];
  if (RES){ v0 += rin[base + t]; v1 += rin[base + t + 256]; }
  __shared__ float red1[4], red2[4];
  int wv = t >> 6;
  float sall = v0 + v1;
  #pragma unroll
  for (int o = 32; o; o >>= 1) sall += __shfl_xor(sall, o, 64);
  if ((t & 63) == 0) red1[wv] = sall;
  __syncthreads();
  float mean = (red1[0] + red1[1] + red1[2] + red1[3]) * (1.f / 512.f);
  float d0 = v0 - mean, d1 = v1 - mean;
  float sq = d0 * d0 + d1 * d1;
  #pragma unroll
  for (int o = 32; o; o >>= 1) sq += __shfl_xor(sq, o, 64);
  if ((t & 63) == 0) red2[wv] = sq;
  __syncthreads();
  float var = (red2[0] + red2[1] + red2[2] + red2[3]) * (1.f / 512.f);
  float rstd = 1.f / sqrtf(var + 1e-5f);
  float y0 = d0 * rstd * sg[t] + bg[t];
  float y1 = d1 * rstd * sg[t + 256] + bg[t + 256];
  outf[base + t] = y0; outf[base + t + 256] = y1;
  outb[base + t] = f2bf(y0); outb[base + t + 256] = f2bf(y1);
}

// ---------------- weight fp32 (K,N) -> bf16 transposed (N,K) ----------------
__global__ __launch_bounds__(256) void wconv_kernel(const float* __restrict__ w,
    unsigned short* __restrict__ wt, int K, int N, size_t sStride, size_t dStride)
{
  __shared__ float tile[32][33];
  const float* wl = w + blockIdx.z * sStride;
  unsigned short* wtl = wt + blockIdx.z * dStride;
  int n0 = blockIdx.x * 32, k0 = blockIdx.y * 32;
  int c = threadIdx.x & 31, r8 = threadIdx.x >> 5;
  #pragma unroll
  for (int p = 0; p < 4; p++){ int r = r8 + p * 8; tile[r][c] = wl[(size_t)(k0 + r) * N + n0 + c]; }
  __syncthreads();
  #pragma unroll
  for (int p = 0; p < 4; p++){ int r = r8 + p * 8; wtl[(size_t)(n0 + r) * K + k0 + c] = f2bf(tile[c][r]); }
}

// ---------------- bf16 MFMA GEMM: C(M,N) = A(M,K) * Wt(N,K)^T ----------------
// Block tile = (32*MR) x (32*NR), 4 waves in 2x2, wave tile = (16MR)x(16NR).
// Double-buffered LDS, 2-phase pipeline: stage(t+1) issued before compute(t),
// single __syncthreads per K-step (implicit vmcnt(0)+lgkmcnt(0) is the drain).
// EPI: 0 = +residual -> f32, 1 = bf16, 2 = bias+gelu -> bf16, 3 = bias+residual -> f32
template<int EPI, int MR, int NR>
__global__ __launch_bounds__(256) void gemm_kernel(
    const unsigned short* __restrict__ A, const unsigned short* __restrict__ Wt,
    float* __restrict__ Cf, unsigned short* __restrict__ Cb,
    const float* __restrict__ bias, const float* __restrict__ Rf, int N, int K)
{
  constexpr int BM = 32 * MR, BN = 32 * NR;
  __shared__ __align__(16) unsigned short As[2][BM * 32];
  __shared__ __align__(16) unsigned short Bs[2][BN * 32];
  const int tid = threadIdx.x;
  const int wv = tid >> 6, lane = tid & 63;
  const int m0 = blockIdx.x * BM, n0 = blockIdx.y * BN;
  const int wm = (wv >> 1) * 16 * MR, wn = (wv & 1) * 16 * NR;
  const int r16 = lane & 15, g = lane >> 4;

  // staging: wave wv loads A rows [8*MR*wv, 8*MR*(wv+1)), same for B; 16 rows/issue
  const unsigned short* gA = A + (size_t)(m0 + 8 * MR * wv + (lane >> 2)) * K + (lane & 3) * 8;
  const unsigned short* gB = Wt + (size_t)(n0 + 8 * NR * wv + (lane >> 2)) * K + (lane & 3) * 8;
  const int lAoff = wv * 8 * MR * 32;
  const int lBoff = wv * 8 * NR * 32;

  f32x4 acc[MR][NR] = {};
  const int nt = K >> 5;

  auto STAGE = [&](int buf, int k0){
    #pragma unroll
    for (int ii = 0; ii < MR / 2; ii++)
      GLD_LDS16(gA + k0 + ii * 16 * K, &As[buf][lAoff + ii * 512]);
    #pragma unroll
    for (int ii = 0; ii < NR / 2; ii++)
      GLD_LDS16(gB + k0 + ii * 16 * K, &Bs[buf][lBoff + ii * 512]);
  };

  STAGE(0, 0);
  __syncthreads();              // drain prologue loads (vmcnt(0))
  int cur = 0;
  for (int t = 0; t < nt; t++){
    if (t + 1 < nt) STAGE(cur ^ 1, (t + 1) * 32);   // prefetch flies under compute
    bf16x8 av[MR], bv[NR];
    #pragma unroll
    for (int m = 0; m < MR; m++)
      av[m] = *reinterpret_cast<const bf16x8*>(&As[cur][(wm + m * 16 + r16) * 32 + g * 8]);
    #pragma unroll
    for (int n = 0; n < NR; n++)
      bv[n] = *reinterpret_cast<const bf16x8*>(&Bs[cur][(wn + n * 16 + r16) * 32 + g * 8]);
    #pragma unroll
    for (int m = 0; m < MR; m++)
      #pragma unroll
      for (int n = 0; n < NR; n++)
        acc[m][n] = __builtin_amdgcn_mfma_f32_16x16x32_bf16(av[m], bv[n], acc[m][n], 0, 0, 0);
    __syncthreads();            // waits prefetch (vmcnt 0) + protects cur for overwrite
    cur ^= 1;
  }

  const int colBase = n0 + wn + r16;
  #pragma unroll
  for (int m = 0; m < MR; m++){
    int rowBase = m0 + wm + m * 16 + g * 4;
    #pragma unroll
    for (int n = 0; n < NR; n++){
      int col = colBase + n * 16;
      float bsv = (EPI >= 2) ? bias[col] : 0.f;
      #pragma unroll
      for (int j = 0; j < 4; j++){
        float vlu = acc[m][n][j];
        if (EPI >= 2) vlu += bsv;
        if (EPI == 2) vlu = 0.5f * vlu * (1.f + erff(vlu * 0.70710678118654752f));
        size_t off = (size_t)(rowBase + j) * N + col;
        if (EPI == 0 || EPI == 3) vlu += Rf[off];
        if (EPI == 1 || EPI == 2) Cb[off] = f2bf(vlu);
        else                      Cf[off] = vlu;
      }
    }
  }
}

// ---------------- sparse tree attention: one wave per (b,n), all 8 heads ----------------
__global__ __launch_bounds__(256) void attn_kernel(
    const unsigned short* __restrict__ qkv, unsigned short* __restrict__ ctx)
{
  int wid = blockIdx.x * 4 + (threadIdx.x >> 6);
  int lane = threadIdx.x & 63;
  int n = wid % NTOT_C;
  int b = wid / NTOT_C;

  int i, sz, of, cb, par;
  if (n < 1024){ i = n;        sz = 1024; of = 0;    cb = -1;            par = 1024 + (i >> 2); }
  else if (n < 1280){ i = n - 1024; sz = 256; of = 1024; cb = 0    + 4 * i; par = 1280 + (i >> 2); }
  else if (n < 1344){ i = n - 1280; sz = 64;  of = 1280; cb = 1024 + 4 * i; par = 1344 + (i >> 2); }
  else if (n < 1360){ i = n - 1344; sz = 16;  of = 1344; cb = 1280 + 4 * i; par = 1360 + (i >> 2); }
  else if (n < 1364){ i = n - 1360; sz = 4;   of = 1360; cb = 1344 + 4 * i; par = 1364; }
  else { i = 0; sz = 1; of = 1364; cb = 1360; par = -1; }

  int nb[10];
  #pragma unroll
  for (int s5 = 0; s5 < 5; s5++){ int pos = i - 2 + s5; nb[s5] = (pos >= 0 && pos < sz) ? of + pos : -1; }
  #pragma unroll
  for (int r = 0; r < 4; r++) nb[5 + r] = (cb >= 0) ? cb + r : -1;
  nb[9] = par;

  const unsigned short* rows = qkv + ((size_t)b * NTOT_C) * 1536;

  u16x8 qv = *reinterpret_cast<const u16x8*>(rows + (size_t)n * 1536 + lane * 8);
  float qf[8];
  #pragma unroll
  for (int e = 0; e < 8; e++) qf[e] = bf2f(qv[e]);

  float sc[10];
  #pragma unroll
  for (int j = 0; j < 10; j++){
    int id = nb[j] >= 0 ? nb[j] : n;
    u16x8 kv = *reinterpret_cast<const u16x8*>(rows + (size_t)id * 1536 + 512 + lane * 8);
    float p = 0.f;
    #pragma unroll
    for (int e = 0; e < 8; e++) p += qf[e] * bf2f(kv[e]);
    p += __shfl_xor(p, 1, 64);
    p += __shfl_xor(p, 2, 64);
    p += __shfl_xor(p, 4, 64);
    sc[j] = (nb[j] >= 0) ? p * 0.125f : -1e30f;
  }
  float mx = sc[0];
  #pragma unroll
  for (int j = 1; j < 10; j++) mx = fmaxf(mx, sc[j]);
  float den = 0.f;
  float wj[10];
  #pragma unroll
  for (int j = 0; j < 10; j++){
    wj[j] = (nb[j] >= 0) ? expf(sc[j] - mx) : 0.f;
    den += wj[j];
  }
  float rden = 1.f / den;
  float accv[8] = {};
  #pragma unroll
  for (int j = 0; j < 10; j++){
    int id = nb[j] >= 0 ? nb[j] : n;
    u16x8 vv = *reinterpret_cast<const u16x8*>(rows + (size_t)id * 1536 + 1024 + lane * 8);
    float w = wj[j];
    #pragma unroll
    for (int e = 0; e < 8; e++) accv[e] += w * bf2f(vv[e]);
  }
  u16x8 ov;
  #pragma unroll
  for (int e = 0; e < 8; e++) ov[e] = f2bf(accv[e] * rden);
  *reinterpret_cast<u16x8*>(ctx + ((size_t)b * NTOT_C + n) * 512 + lane * 8) = ov;
}

// ---------------- gather effective prefixes -> output ----------------
__global__ __launch_bounds__(256) void gather_kernel(const float* __restrict__ seqf,
    float* __restrict__ out)
{
  int e = blockIdx.x * 256 + threadIdx.x;
  int d = e & 511;
  int r = e >> 9;
  int j = r % 1334;
  int b = r / 1334;
  int src;
  if      (j < 1000) src = j;
  else if (j < 1250) src = j + 24;
  else if (j < 1313) src = j + 30;
  else if (j < 1333) src = j + 31;
  else               src = 1364;
  out[e] = seqf[((size_t)b * NTOT_C + src) * 512 + d];
}

extern "C" void kernel_launch(void* const* d_in, const int* in_sizes, int n_in,
                              void* d_out, int out_size, void* d_ws, size_t ws_size,
                              hipStream_t stream)
{
  const float* x      = (const float*)d_in[0];
  const float* conv_w = (const float*)d_in[1];
  const float* norm_s = (const float*)d_in[2];
  const float* norm_b = (const float*)d_in[3];
  const float* wq     = (const float*)d_in[4];
  const float* wk     = (const float*)d_in[5];
  const float* wv     = (const float*)d_in[6];
  const float* wo     = (const float*)d_in[7];
  const float* ln1_s  = (const float*)d_in[8];
  const float* ln1_b  = (const float*)d_in[9];
  const float* w1     = (const float*)d_in[10];
  const float* b1     = (const float*)d_in[11];
  const float* w2     = (const float*)d_in[12];
  const float* b2     = (const float*)d_in[13];
  const float* ln2_s  = (const float*)d_in[14];
  const float* ln2_b  = (const float*)d_in[15];
  float* out = (float*)d_out;

  char* ws = (char*)d_ws;
  size_t off = 0;
  auto alloc = [&](size_t bytes) -> char* {
    char* p = ws + off; off += (bytes + 255) & ~(size_t)255; return p;
  };
  unsigned short* qkvT = (unsigned short*)alloc((size_t)NLAY * 1536 * 512 * 2);
  unsigned short* woT  = (unsigned short*)alloc((size_t)NLAY * 512 * 512 * 2);
  unsigned short* w1T  = (unsigned short*)alloc((size_t)NLAY * 2048 * 512 * 2);
  unsigned short* w2T  = (unsigned short*)alloc((size_t)NLAY * 512 * 2048 * 2);
  float*          seqf = (float*)alloc((size_t)M_PAD * 512 * 4);
  unsigned short* seqb = (unsigned short*)alloc((size_t)M_PAD * 512 * 2);
  float*          buff = (float*)alloc((size_t)M_PAD * 512 * 4);
  unsigned short* qkvb = (unsigned short*)alloc((size_t)M_PAD * 1536 * 2);
  unsigned short* ctxb = (unsigned short*)alloc((size_t)M_PAD * 512 * 2);
  unsigned short* ffn1 = qkvb;  // alias
  float*          pe   = buff;  // alias: PE table pre-loop

  wconv_kernel<<<dim3(16,16,NLAY),256,0,stream>>>(wq, qkvT,              512,  512,  (size_t)512*512,  (size_t)1536*512);
  wconv_kernel<<<dim3(16,16,NLAY),256,0,stream>>>(wk, qkvT + 512*512,    512,  512,  (size_t)512*512,  (size_t)1536*512);
  wconv_kernel<<<dim3(16,16,NLAY),256,0,stream>>>(wv, qkvT + 1024*512,   512,  512,  (size_t)512*512,  (size_t)1536*512);
  wconv_kernel<<<dim3(16,16,NLAY),256,0,stream>>>(wo, woT,               512,  512,  (size_t)512*512,  (size_t)512*512);
  wconv_kernel<<<dim3(64,16,NLAY),256,0,stream>>>(w1, w1T,               512,  2048, (size_t)512*2048, (size_t)512*2048);
  wconv_kernel<<<dim3(16,64,NLAY),256,0,stream>>>(w2, w2T,               2048, 512,  (size_t)2048*512, (size_t)2048*512);

  pe_kernel<<<(SEQN * 512) / 256, 256, 0, stream>>>(pe);
  conv_kernel<<<dim3(4,16,BQ), 256, 0, stream>>>(x, conv_w, pe, seqf);
  const int psz[6]  = {1024, 256, 64, 16, 4, 1};
  const int poff[6] = {0, 1024, 1280, 1344, 1360, 1364};
  for (int l = 0; l < 5; l++)
    pool_kernel<<<(BQ * psz[l+1] * 512) / 256, 256, 0, stream>>>(seqf, poff[l], poff[l+1], psz[l+1]);
  ln_kernel<false><<<M_PAD, 256, 0, stream>>>(seqf, nullptr, seqf, seqb, norm_s, norm_b, M_REAL);

  for (int l = 0; l < NLAY; l++){
    // QKV: 128x128 tiles, grid 86x12
    gemm_kernel<1,4,4><<<dim3(86,12),256,0,stream>>>(seqb, qkvT + (size_t)l*1536*512, nullptr, qkvb, nullptr, nullptr, 1536, 512);
    attn_kernel<<<(BQ * NTOT_C + 3) / 4, 256, 0, stream>>>(qkvb, ctxb);
    // WO: 64x64 tiles, grid 172x8 (occupancy fix for N=512)
    gemm_kernel<0,2,2><<<dim3(172,8),256,0,stream>>>(ctxb, woT + (size_t)l*512*512, buff, nullptr, nullptr, seqf, 512, 512);
    ln_kernel<false><<<M_PAD,256,0,stream>>>(buff, nullptr, seqf, seqb, ln1_s + l*512, ln1_b + l*512, M_REAL);
    // FFN1: 128x128 tiles, grid 86x16
    gemm_kernel<2,4,4><<<dim3(86,16),256,0,stream>>>(seqb, w1T + (size_t)l*2048*512, nullptr, ffn1, b1 + l*2048, nullptr, 2048, 512);
    // FFN2: 64x128 tiles, grid 172x4
    gemm_kernel<3,2,4><<<dim3(172,4),256,0,stream>>>(ffn1, w2T + (size_t)l*512*2048, buff, nullptr, b2 + l*512, seqf, 512, 2048);
    ln_kernel<false><<<M_PAD,256,0,stream>>>(buff, nullptr, seqf, seqb, ln2_s + l*512, ln2_b + l*512, M_REAL);
  }

  gather_kernel<<<(BQ * 1334 * 512) / 256, 256, 0, stream>>>(seqf, out);
}

// Round 6
// 838.940 us; speedup vs baseline: 1.4127x; 1.0057x over previous
//
#include <hip/hip_runtime.h>
#include <cstdint>
#include <math.h>

#define DEV __device__ __forceinline__

static constexpr int BQ = 8, SEQN = 1000, CIN = 32, NH = 8;
static constexpr int NLAY = 4;
static constexpr int NTOT_C = 1365;
static constexpr int M_REAL = BQ * NTOT_C;   // 10920
static constexpr int M_PAD  = 11008;         // 86 * 128 = 172 * 64

DEV float bf2f(unsigned short u){ return __uint_as_float(((unsigned)u) << 16); }
DEV unsigned short f2bf(float f){
  unsigned u = __float_as_uint(f);
  u += 0x7fffu + ((u >> 16) & 1u);
  return (unsigned short)(u >> 16);
}

typedef __bf16 bf16x8 __attribute__((ext_vector_type(8)));
typedef float  f32x4  __attribute__((ext_vector_type(4)));
typedef unsigned short u16x8 __attribute__((ext_vector_type(8)));

#define GLD_LDS16(gp, lp) __builtin_amdgcn_global_load_lds( \
    (const __attribute__((address_space(1))) void*)(gp), \
    (__attribute__((address_space(3))) void*)(lp), 16, 0, 0)

template<int N> DEV void waitcnt_vm(){
  asm volatile("s_waitcnt vmcnt(%0)" :: "i"(N) : "memory");
}
DEV void cfence(){ asm volatile("" ::: "memory"); }

// ---------------- sinusoid PE table (fp32), SEQN x 512 ----------------
__global__ __launch_bounds__(256) void pe_kernel(float* __restrict__ pe)
{
  int idx = blockIdx.x * 256 + threadIdx.x;
  int d = idx & 511, s = idx >> 9;
  if (s >= SEQN) return;
  float e2 = (float)(d & ~1);
  float freq = exp2f(e2 * (-13.287712379549449f / 512.0f));
  float ang = (float)s * freq;
  pe[idx] = (d & 1) ? cosf(ang) : sinf(ang);
}

// ---------------- conv1d (k=3 circular), tiled: 64 s x 128 d per block ----------------
__global__ __launch_bounds__(256) void conv_kernel(const float* __restrict__ x,
    const float* __restrict__ w, const float* __restrict__ pe, float* __restrict__ seqf)
{
  __shared__ float ws_w[128 * 97];
  __shared__ __align__(16) float xs[66][32];
  int b = blockIdx.z, s0 = blockIdx.y * 64, d0 = blockIdx.x * 128;
  int tid = threadIdx.x;
  for (int i = tid; i < 128 * 96; i += 256){
    int r = i / 96, c = i - r * 96;
    ws_w[r * 97 + c] = w[(size_t)(d0 + r) * 96 + c];
  }
  for (int i = tid; i < 66 * 32; i += 256){
    int r = i >> 5, c = i & 31;
    int ss = s0 + r - 1;
    ss = (ss < 0) ? (ss + SEQN) : (ss >= SEQN ? ss - SEQN : ss);
    xs[r][c] = x[((size_t)b * SEQN + ss) * CIN + c];
  }
  __syncthreads();
  int dl = tid & 127, sh = tid >> 7;
  float wr[96];
  #pragma unroll
  for (int i = 0; i < 96; i++) wr[i] = ws_w[dl * 97 + i];
  int d = d0 + dl;
  for (int si = 0; si < 32; si++){
    int sl = sh * 32 + si;
    int s = s0 + sl;
    float acc = 0.f;
    #pragma unroll
    for (int kk = 0; kk < 3; kk++){
      const float* xr = xs[sl + kk];
      #pragma unroll
      for (int c = 0; c < 32; c++) acc += xr[c] * wr[c * 3 + kk];
    }
    float outv = (s < SEQN) ? acc + pe[(size_t)s * 512 + d] : 0.f;
    seqf[((size_t)b * NTOT_C + s) * 512 + d] = outv;
  }
}

// ---------------- max-pool one pyramid level ----------------
__global__ __launch_bounds__(256) void pool_kernel(float* __restrict__ seqf,
    int inOff, int outOff, int outSz)
{
  int e = blockIdx.x * 256 + threadIdx.x;
  int d = e & 511;
  int r = e >> 9;
  int i = r % outSz;
  int b = r / outSz;
  const float* src = seqf + ((size_t)b * NTOT_C + inOff + 4 * i) * 512 + d;
  float m = fmaxf(fmaxf(src[0], src[512]), fmaxf(src[1024], src[1536]));
  seqf[((size_t)b * NTOT_C + outOff + i) * 512 + d] = m;
}

// ---------------- LayerNorm, emits fp32 + bf16 ----------------
template<bool RES>
__global__ __launch_bounds__(256) void ln_kernel(const float* __restrict__ xin,
    const float* __restrict__ rin, float* __restrict__ outf, unsigned short* __restrict__ outb,
    const float* __restrict__ sg, const float* __restrict__ bg, int M)
{
  int row = blockIdx.x;
  int t = threadIdx.x;
  size_t base = (size_t)row * 512;
  if (row >= M){ outb[base + t] = 0; outb[base + t + 256] = 0; return; }
  float v0 = xin[base + t], v1 = xin[base + t + 256];
  if (RES){ v0 += rin[base + t]; v1 += rin[base + t + 256]; }
  __shared__ float red1[4], red2[4];
  int wv = t >> 6;
  float sall = v0 + v1;
  #pragma unroll
  for (int o = 32; o; o >>= 1) sall += __shfl_xor(sall, o, 64);
  if ((t & 63) == 0) red1[wv] = sall;
  __syncthreads();
  float mean = (red1[0] + red1[1] + red1[2] + red1[3]) * (1.f / 512.f);
  float d0 = v0 - mean, d1 = v1 - mean;
  float sq = d0 * d0 + d1 * d1;
  #pragma unroll
  for (int o = 32; o; o >>= 1) sq += __shfl_xor(sq, o, 64);
  if ((t & 63) == 0) red2[wv] = sq;
  __syncthreads();
  float var = (red2[0] + red2[1] + red2[2] + red2[3]) * (1.f / 512.f);
  float rstd = 1.f / sqrtf(var + 1e-5f);
  float y0 = d0 * rstd * sg[t] + bg[t];
  float y1 = d1 * rstd * sg[t + 256] + bg[t + 256];
  outf[base + t] = y0; outf[base + t + 256] = y1;
  outb[base + t] = f2bf(y0); outb[base + t + 256] = f2bf(y1);
}

// ---------------- weight fp32 (K,N) -> bf16 transposed (N,K) ----------------
__global__ __launch_bounds__(256) void wconv_kernel(const float* __restrict__ w,
    unsigned short* __restrict__ wt, int K, int N, size_t sStride, size_t dStride)
{
  __shared__ float tile[32][33];
  const float* wl = w + blockIdx.z * sStride;
  unsigned short* wtl = wt + blockIdx.z * dStride;
  int n0 = blockIdx.x * 32, k0 = blockIdx.y * 32;
  int c = threadIdx.x & 31, r8 = threadIdx.x >> 5;
  #pragma unroll
  for (int p = 0; p < 4; p++){ int r = r8 + p * 8; tile[r][c] = wl[(size_t)(k0 + r) * N + n0 + c]; }
  __syncthreads();
  #pragma unroll
  for (int p = 0; p < 4; p++){ int r = r8 + p * 8; wtl[(size_t)(n0 + r) * K + k0 + c] = f2bf(tile[c][r]); }
}

// ---------------- bf16 MFMA GEMM: C(M,N) = A(M,K) * Wt(N,K)^T ----------------
// Block tile = (32*MR) x (32*NR), 4 waves in 2x2.
// 3-slot LDS, 2-deep prefetch, counted vmcnt (never 0 in steady state), raw
// s_barrier + compiler fences. LDS XOR-swizzle: linear gld_lds dest,
// inverse-swizzled global source (cg ^ ((row>>1)&3)), same XOR on ds_read.
// EPI: 0 = +residual -> f32, 1 = bf16, 2 = bias+gelu -> bf16, 3 = bias+residual -> f32
template<int EPI, int MR, int NR>
__global__ __launch_bounds__(256) void gemm_kernel(
    const unsigned short* __restrict__ A, const unsigned short* __restrict__ Wt,
    float* __restrict__ Cf, unsigned short* __restrict__ Cb,
    const float* __restrict__ bias, const float* __restrict__ Rf, int N, int K)
{
  constexpr int BM = 32 * MR, BN = 32 * NR;
  constexpr int SLOT_A = BM * 32, SLOT_B = BN * 32;   // ushorts per slot
  constexpr int L = MR / 2 + NR / 2;                  // gld_lds per wave per stage
  __shared__ __align__(16) unsigned short As[3][SLOT_A];
  __shared__ __align__(16) unsigned short Bs[3][SLOT_B];
  const int tid = threadIdx.x;
  const int wv = tid >> 6, lane = tid & 63;
  const int m0 = blockIdx.x * BM, n0 = blockIdx.y * BN;
  const int wm = (wv >> 1) * 16 * MR, wn = (wv & 1) * 16 * NR;
  const int r16 = lane & 15, g = lane >> 4;

  // staging source: lane -> (row = lane>>2, colgrp = lane&3); source colgrp
  // pre-swizzled so linear LDS dest ends up XOR-swizzled (rule #21 involution)
  const int lrow = lane >> 2;
  const int scg  = (lane & 3) ^ ((lrow >> 1) & 3);
  const unsigned short* gA = A + (size_t)(m0 + 8 * MR * wv + lrow) * K + scg * 8;
  const unsigned short* gB = Wt + (size_t)(n0 + 8 * NR * wv + lrow) * K + scg * 8;
  const int lAoff = wv * 8 * MR * 32;
  const int lBoff = wv * 8 * NR * 32;

  f32x4 acc[MR][NR] = {};
  const int nt = K >> 5;

  auto STAGE = [&](int slot, int k0){
    #pragma unroll
    for (int ii = 0; ii < MR / 2; ii++)
      GLD_LDS16(gA + k0 + ii * 16 * K, &As[slot][lAoff + ii * 512]);
    #pragma unroll
    for (int ii = 0; ii < NR / 2; ii++)
      GLD_LDS16(gB + k0 + ii * 16 * K, &Bs[slot][lBoff + ii * 512]);
  };

  STAGE(0, 0);
  STAGE(1, 32);
  int cur = 0;
  const int rswz = (g ^ ((r16 >> 1) & 3)) * 8;   // read-side XOR (same involution)
  for (int t = 0; t < nt; t++){
    int s2 = (cur == 0) ? 2 : cur - 1;           // (cur+2)%3
    if (t + 2 < nt) STAGE(s2, (t + 2) * 32);
    if (t + 2 < nt)      waitcnt_vm<2 * L>();    // own slot-cur loads done
    else if (t + 1 < nt) waitcnt_vm<L>();
    else                 waitcnt_vm<0>();
    __builtin_amdgcn_s_barrier();                // all waves verified slot cur
    cfence();                                    // no ds_read hoists above barrier
    bf16x8 av[MR], bv[NR];
    #pragma unroll
    for (int m = 0; m < MR; m++)
      av[m] = *reinterpret_cast<const bf16x8*>(&As[cur][(wm + m * 16 + r16) * 32 + rswz]);
    #pragma unroll
    for (int n = 0; n < NR; n++)
      bv[n] = *reinterpret_cast<const bf16x8*>(&Bs[cur][(wn + n * 16 + r16) * 32 + rswz]);
    __builtin_amdgcn_s_setprio(1);
    #pragma unroll
    for (int m = 0; m < MR; m++)
      #pragma unroll
      for (int n = 0; n < NR; n++)
        acc[m][n] = __builtin_amdgcn_mfma_f32_16x16x32_bf16(av[m], bv[n], acc[m][n], 0, 0, 0);
    __builtin_amdgcn_s_setprio(0);
    __builtin_amdgcn_s_barrier();                // reads of cur done before overwrite
    cfence();                                    // next STAGE can't hoist above
    cur = (cur == 2) ? 0 : cur + 1;
  }

  const int colBase = n0 + wn + r16;
  #pragma unroll
  for (int m = 0; m < MR; m++){
    int rowBase = m0 + wm + m * 16 + g * 4;
    #pragma unroll
    for (int n = 0; n < NR; n++){
      int col = colBase + n * 16;
      float bsv = (EPI >= 2) ? bias[col] : 0.f;
      #pragma unroll
      for (int j = 0; j < 4; j++){
        float vlu = acc[m][n][j];
        if (EPI >= 2) vlu += bsv;
        if (EPI == 2) vlu = 0.5f * vlu * (1.f + erff(vlu * 0.70710678118654752f));
        size_t off = (size_t)(rowBase + j) * N + col;
        if (EPI == 0 || EPI == 3) vlu += Rf[off];
        if (EPI == 1 || EPI == 2) Cb[off] = f2bf(vlu);
        else                      Cf[off] = vlu;
      }
    }
  }
}

// ---------------- sparse tree attention: one wave per (b,n), all 8 heads ----------------
__global__ __launch_bounds__(256) void attn_kernel(
    const unsigned short* __restrict__ qkv, unsigned short* __restrict__ ctx)
{
  int wid = blockIdx.x * 4 + (threadIdx.x >> 6);
  int lane = threadIdx.x & 63;
  int n = wid % NTOT_C;
  int b = wid / NTOT_C;

  int i, sz, of, cb, par;
  if (n < 1024){ i = n;        sz = 1024; of = 0;    cb = -1;            par = 1024 + (i >> 2); }
  else if (n < 1280){ i = n - 1024; sz = 256; of = 1024; cb = 0    + 4 * i; par = 1280 + (i >> 2); }
  else if (n < 1344){ i = n - 1280; sz = 64;  of = 1280; cb = 1024 + 4 * i; par = 1344 + (i >> 2); }
  else if (n < 1360){ i = n - 1344; sz = 16;  of = 1344; cb = 1280 + 4 * i; par = 1360 + (i >> 2); }
  else if (n < 1364){ i = n - 1360; sz = 4;   of = 1360; cb = 1344 + 4 * i; par = 1364; }
  else { i = 0; sz = 1; of = 1364; cb = 1360; par = -1; }

  int nb[10];
  #pragma unroll
  for (int s5 = 0; s5 < 5; s5++){ int pos = i - 2 + s5; nb[s5] = (pos >= 0 && pos < sz) ? of + pos : -1; }
  #pragma unroll
  for (int r = 0; r < 4; r++) nb[5 + r] = (cb >= 0) ? cb + r : -1;
  nb[9] = par;

  const unsigned short* rows = qkv + ((size_t)b * NTOT_C) * 1536;

  u16x8 qv = *reinterpret_cast<const u16x8*>(rows + (size_t)n * 1536 + lane * 8);
  float qf[8];
  #pragma unroll
  for (int e = 0; e < 8; e++) qf[e] = bf2f(qv[e]);

  float sc[10];
  #pragma unroll
  for (int j = 0; j < 10; j++){
    int id = nb[j] >= 0 ? nb[j] : n;
    u16x8 kv = *reinterpret_cast<const u16x8*>(rows + (size_t)id * 1536 + 512 + lane * 8);
    float p = 0.f;
    #pragma unroll
    for (int e = 0; e < 8; e++) p += qf[e] * bf2f(kv[e]);
    p += __shfl_xor(p, 1, 64);
    p += __shfl_xor(p, 2, 64);
    p += __shfl_xor(p, 4, 64);
    sc[j] = (nb[j] >= 0) ? p * 0.125f : -1e30f;
  }
  float mx = sc[0];
  #pragma unroll
  for (int j = 1; j < 10; j++) mx = fmaxf(mx, sc[j]);
  float den = 0.f;
  float wj[10];
  #pragma unroll
  for (int j = 0; j < 10; j++){
    wj[j] = (nb[j] >= 0) ? expf(sc[j] - mx) : 0.f;
    den += wj[j];
  }
  float rden = 1.f / den;
  float accv[8] = {};
  #pragma unroll
  for (int j = 0; j < 10; j++){
    int id = nb[j] >= 0 ? nb[j] : n;
    u16x8 vv = *reinterpret_cast<const u16x8*>(rows + (size_t)id * 1536 + 1024 + lane * 8);
    float w = wj[j];
    #pragma unroll
    for (int e = 0; e < 8; e++) accv[e] += w * bf2f(vv[e]);
  }
  u16x8 ov;
  #pragma unroll
  for (int e = 0; e < 8; e++) ov[e] = f2bf(accv[e] * rden);
  *reinterpret_cast<u16x8*>(ctx + ((size_t)b * NTOT_C + n) * 512 + lane * 8) = ov;
}

// ---------------- gather effective prefixes -> output ----------------
__global__ __launch_bounds__(256) void gather_kernel(const float* __restrict__ seqf,
    float* __restrict__ out)
{
  int e = blockIdx.x * 256 + threadIdx.x;
  int d = e & 511;
  int r = e >> 9;
  int j = r % 1334;
  int b = r / 1334;
  int src;
  if      (j < 1000) src = j;
  else if (j < 1250) src = j + 24;
  else if (j < 1313) src = j + 30;
  else if (j < 1333) src = j + 31;
  else               src = 1364;
  out[e] = seqf[((size_t)b * NTOT_C + src) * 512 + d];
}

extern "C" void kernel_launch(void* const* d_in, const int* in_sizes, int n_in,
                              void* d_out, int out_size, void* d_ws, size_t ws_size,
                              hipStream_t stream)
{
  const float* x      = (const float*)d_in[0];
  const float* conv_w = (const float*)d_in[1];
  const float* norm_s = (const float*)d_in[2];
  const float* norm_b = (const float*)d_in[3];
  const float* wq     = (const float*)d_in[4];
  const float* wk     = (const float*)d_in[5];
  const float* wv     = (const float*)d_in[6];
  const float* wo     = (const float*)d_in[7];
  const float* ln1_s  = (const float*)d_in[8];
  const float* ln1_b  = (const float*)d_in[9];
  const float* w1     = (const float*)d_in[10];
  const float* b1     = (const float*)d_in[11];
  const float* w2     = (const float*)d_in[12];
  const float* b2     = (const float*)d_in[13];
  const float* ln2_s  = (const float*)d_in[14];
  const float* ln2_b  = (const float*)d_in[15];
  float* out = (float*)d_out;

  char* ws = (char*)d_ws;
  size_t off = 0;
  auto alloc = [&](size_t bytes) -> char* {
    char* p = ws + off; off += (bytes + 255) & ~(size_t)255; return p;
  };
  unsigned short* qkvT = (unsigned short*)alloc((size_t)NLAY * 1536 * 512 * 2);
  unsigned short* woT  = (unsigned short*)alloc((size_t)NLAY * 512 * 512 * 2);
  unsigned short* w1T  = (unsigned short*)alloc((size_t)NLAY * 2048 * 512 * 2);
  unsigned short* w2T  = (unsigned short*)alloc((size_t)NLAY * 512 * 2048 * 2);
  float*          seqf = (float*)alloc((size_t)M_PAD * 512 * 4);
  unsigned short* seqb = (unsigned short*)alloc((size_t)M_PAD * 512 * 2);
  float*          buff = (float*)alloc((size_t)M_PAD * 512 * 4);
  unsigned short* qkvb = (unsigned short*)alloc((size_t)M_PAD * 1536 * 2);
  unsigned short* ctxb = (unsigned short*)alloc((size_t)M_PAD * 512 * 2);
  unsigned short* ffn1 = qkvb;  // alias
  float*          pe   = buff;  // alias: PE table pre-loop

  wconv_kernel<<<dim3(16,16,NLAY),256,0,stream>>>(wq, qkvT,              512,  512,  (size_t)512*512,  (size_t)1536*512);
  wconv_kernel<<<dim3(16,16,NLAY),256,0,stream>>>(wk, qkvT + 512*512,    512,  512,  (size_t)512*512,  (size_t)1536*512);
  wconv_kernel<<<dim3(16,16,NLAY),256,0,stream>>>(wv, qkvT + 1024*512,   512,  512,  (size_t)512*512,  (size_t)1536*512);
  wconv_kernel<<<dim3(16,16,NLAY),256,0,stream>>>(wo, woT,               512,  512,  (size_t)512*512,  (size_t)512*512);
  wconv_kernel<<<dim3(64,16,NLAY),256,0,stream>>>(w1, w1T,               512,  2048, (size_t)512*2048, (size_t)512*2048);
  wconv_kernel<<<dim3(16,64,NLAY),256,0,stream>>>(w2, w2T,               2048, 512,  (size_t)2048*512, (size_t)2048*512);

  pe_kernel<<<(SEQN * 512) / 256, 256, 0, stream>>>(pe);
  conv_kernel<<<dim3(4,16,BQ), 256, 0, stream>>>(x, conv_w, pe, seqf);
  const int psz[6]  = {1024, 256, 64, 16, 4, 1};
  const int poff[6] = {0, 1024, 1280, 1344, 1360, 1364};
  for (int l = 0; l < 5; l++)
    pool_kernel<<<(BQ * psz[l+1] * 512) / 256, 256, 0, stream>>>(seqf, poff[l], poff[l+1], psz[l+1]);
  ln_kernel<false><<<M_PAD, 256, 0, stream>>>(seqf, nullptr, seqf, seqb, norm_s, norm_b, M_REAL);

  for (int l = 0; l < NLAY; l++){
    // QKV: 128x128 tiles, grid 86x12
    gemm_kernel<1,4,4><<<dim3(86,12),256,0,stream>>>(seqb, qkvT + (size_t)l*1536*512, nullptr, qkvb, nullptr, nullptr, 1536, 512);
    attn_kernel<<<(BQ * NTOT_C + 3) / 4, 256, 0, stream>>>(qkvb, ctxb);
    // WO: 64x64 tiles, grid 172x8
    gemm_kernel<0,2,2><<<dim3(172,8),256,0,stream>>>(ctxb, woT + (size_t)l*512*512, buff, nullptr, nullptr, seqf, 512, 512);
    ln_kernel<false><<<M_PAD,256,0,stream>>>(buff, nullptr, seqf, seqb, ln1_s + l*512, ln1_b + l*512, M_REAL);
    // FFN1: 128x128 tiles, grid 86x16
    gemm_kernel<2,4,4><<<dim3(86,16),256,0,stream>>>(seqb, w1T + (size_t)l*2048*512, nullptr, ffn1, b1 + l*2048, nullptr, 2048, 512);
    // FFN2: 64x128 tiles, grid 172x4
    gemm_kernel<3,2,4><<<dim3(172,4),256,0,stream>>>(ffn1, w2T + (size_t)l*512*2048, buff, nullptr, b2 + l*512, seqf, 512, 2048);
    ln_kernel<false><<<M_PAD,256,0,stream>>>(buff, nullptr, seqf, seqb, ln2_s + l*512, ln2_b + l*512, M_REAL);
  }

  gather_kernel<<<(BQ * 1334 * 512) / 256, 256, 0, stream>>>(seqf, out);
}